// Round 13
// baseline (214.258 us; speedup 1.0000x reference)
//
#include <hip/hip_runtime.h>
#include <hip/hip_bf16.h>
#include <math.h>

// PostEncode R13: window GEMM + reg-free async staging (R12) +
//  - mega-pre kernel: conv / setup / bucket+wdesc / pack in ONE launch
//    (independent block ranges) -> pre-chain overlapped, 4 launches -> 2
//  - abase/post prefetched into LDS via global_load_lds width-4 at loop top
//    (drained B1; ab read in L3 after B2, po read in own-wave finish;
//    single-buffered is race-free: prior reads precede next top-of-loop
//    write by >=1 barrier or program order)
//  - fused grid 2048 (tail smoothing), prologue guarded by Wtot, int4 wdesc

#define NN 16384
#define LL 50
#define EE 64
#define NUE 6400000  // u2e bf16 elements; r2e table follows

typedef __attribute__((ext_vector_type(8))) short short8;
typedef __attribute__((ext_vector_type(4))) float f32x4;

static __device__ __forceinline__ unsigned short f2bf(float x) {
  __hip_bfloat16 h = __float2bfloat16(x);
  unsigned short u;
  __builtin_memcpy(&u, &h, 2);
  return u;
}

static __device__ __forceinline__ float bf2f(unsigned short u) {
  unsigned int v = ((unsigned int)u) << 16;
  float f;
  __builtin_memcpy(&f, &v, 4);
  return f;
}

static __device__ __forceinline__ f32x4 ld4(const float* p) {
  return *(const f32x4*)p;
}

static __device__ __forceinline__ f32x4 relu4(f32x4 a) {
  f32x4 r;
  r[0] = fmaxf(a[0], 0.f); r[1] = fmaxf(a[1], 0.f);
  r[2] = fmaxf(a[2], 0.f); r[3] = fmaxf(a[3], 0.f);
  return r;
}

// async global->LDS; lds dest = wave-uniform base + lane*size
static __device__ __forceinline__ void gl_lds16(const unsigned short* g,
                                                unsigned char* l) {
  __builtin_amdgcn_global_load_lds(
      (const __attribute__((address_space(1))) void*)g,
      (__attribute__((address_space(3))) void*)l, 16, 0, 0);
}
static __device__ __forceinline__ void gl_lds4(const float* g, float* l) {
  __builtin_amdgcn_global_load_lds(
      (const __attribute__((address_space(1))) void*)g,
      (__attribute__((address_space(3))) void*)l, 4, 0, 0);
}

#define MFMA(A, B, C) __builtin_amdgcn_mfma_f32_16x16x32_bf16((A), (B), (C), 0, 0, 0)
#define SWZ(row, byteoff) ((byteoff) ^ (((row) & 7) << 4))

// ---------------- mega-pre: conv | setup | bucket+wdesc | pack ------------
// blocks [0,2048): conv ; [2048,6144): setup (4 nodes/block) ;
// 6144: bucket+wdesc ; [6145,6155): pack.
// dsc encode: node(14) | tile(2)<<14 | len(6)<<16 ; -1 = empty slot.
__global__ __launch_bounds__(256)
void pre_kernel(const float* __restrict__ u2e, const float* __restrict__ r2e,
                const float* __restrict__ content_emb,
                const int* __restrict__ pr_content,
                const float* __restrict__ We_w, const float* __restrict__ We_b,
                const float* __restrict__ W1_w, const float* __restrict__ W2_w,
                const float* __restrict__ A1_w, const float* __restrict__ A1_b,
                const float* __restrict__ A2_w,
                const int* __restrict__ lengths,
                unsigned short* __restrict__ ur_bf,
                int* __restrict__ buckets, int* __restrict__ wdesc,
                int* __restrict__ Wout, unsigned short* __restrict__ frag_ws,
                float* __restrict__ post_ws, float* __restrict__ abase_ws) {
  const int b = blockIdx.x;
  const int tid = (int)threadIdx.x;
  __shared__ float ce_s[4][128];
  __shared__ float post_s[4][64];
  __shared__ int cnt_s[4];

  if (b < 2048) {
    // ---- conv: u2e,r2e f32 -> bf16 tables ----
    const int total8 = (NUE + 384) / 8;
    for (int i = b * 256 + tid; i < total8; i += 2048 * 256) {
      const long long e0 = (long long)i * 8;
      const float* src = (e0 < NUE) ? (u2e + e0) : (r2e + (e0 - NUE));
      float4 a = *(const float4*)src;
      float4 bb = *(const float4*)(src + 4);
      short8 v;
      v[0] = (short)f2bf(a.x); v[1] = (short)f2bf(a.y);
      v[2] = (short)f2bf(a.z); v[3] = (short)f2bf(a.w);
      v[4] = (short)f2bf(bb.x); v[5] = (short)f2bf(bb.y);
      v[6] = (short)f2bf(bb.z); v[7] = (short)f2bf(bb.w);
      *reinterpret_cast<short8*>(ur_bf + e0) = v;
    }
  } else if (b < 6144) {
    // ---- setup: post + abase, 4 nodes/block ----
    const int sub = tid >> 6;
    const int e = tid & 63;
    const int n = (b - 2048) * 4 + sub;
    const float* ce = content_emb + (size_t)pr_content[n] * 128;
    ce_s[sub][e] = ce[e];
    ce_s[sub][64 + e] = ce[64 + e];
    __syncthreads();
    float acc = We_b[e];
#pragma unroll 8
    for (int k = 0; k < 128; ++k)
      acc = fmaf(ce_s[sub][k], We_w[k * EE + e], acc);
    float po = fmaxf(acc, 0.f);
    post_s[sub][e] = po;
    post_ws[(size_t)n * EE + e] = po;
    __syncthreads();
    float ab = A1_b[e];
#pragma unroll 8
    for (int k = 0; k < 64; ++k)
      ab = fmaf(post_s[sub][k], A1_w[(64 + k) * EE + e], ab);
    abase_ws[(size_t)n * EE + e] = ab;
  } else if (b == 6144) {
    // ---- bucket (ballot-aggregated) + wdesc ----
    const int lanei = tid & 63;
    if (tid < 4) cnt_s[tid] = 0;
    __syncthreads();
    for (int i0 = 0; i0 < NN; i0 += 256) {
      const int n = i0 + tid;
      const int nt = (lengths[n] + 15) >> 4;  // 1..4
#pragma unroll
      for (int bb = 1; bb <= 4; ++bb) {
        const unsigned long long mask = __ballot(nt == bb);
        if (mask) {
          const int leader = __ffsll((long long)mask) - 1;
          int base = 0;
          if (lanei == leader)
            base = atomicAdd(&cnt_s[bb - 1], (int)__popcll(mask));
          base = __shfl(base, leader);
          if (nt == bb) {
            const int rank = __popcll(mask & ((1ull << lanei) - 1ull));
            buckets[(bb - 1) * NN + base + rank] = n;
          }
        }
      }
    }
    __syncthreads();

    const int c1 = cnt_s[0], c2 = cnt_s[1], c3 = cnt_s[2], c4 = cnt_s[3];
    const int u1 = (c1 < c3) ? c1 : c3;
    const int p2 = c2 >> 1, odd2 = c2 & 1;
    const int rem1 = c1 - u1;
    const int o2ones = odd2 ? ((rem1 < 2) ? rem1 : 2) : 0;
    const int rem1b = rem1 - o2ones;
    const int w4 = c4, w3 = c3, w2 = p2 + odd2, w1 = (rem1b + 3) >> 2;
    const int W = w4 + w3 + w2 + w1;
    if (tid == 0) *Wout = W;

    const int* b1 = buckets;
    const int* b2 = buckets + NN;
    const int* b3 = buckets + 2 * NN;
    const int* b4 = buckets + 3 * NN;
#define ENC(n, t) ((n) | ((t) << 14) | (lengths[(n)] << 16))
    for (int w = tid; w < W; w += 256) {
      int d0 = -1, d1 = -1, d2 = -1, d3 = -1;
      if (w < w4) {
        const int n = b4[w];
        d0 = ENC(n, 0); d1 = ENC(n, 1); d2 = ENC(n, 2); d3 = ENC(n, 3);
      } else if (w < w4 + w3) {
        const int i = w - w4;
        const int n = b3[i];
        d0 = ENC(n, 0); d1 = ENC(n, 1); d2 = ENC(n, 2);
        if (i < u1) d3 = ENC(b1[i], 0);
      } else if (w < w4 + w3 + w2) {
        const int i = w - w4 - w3;
        if (i < p2) {
          const int a = b2[2 * i], bbn = b2[2 * i + 1];
          d0 = ENC(a, 0); d1 = ENC(a, 1); d2 = ENC(bbn, 0); d3 = ENC(bbn, 1);
        } else {
          const int a = b2[c2 - 1];
          d0 = ENC(a, 0); d1 = ENC(a, 1);
          if (o2ones > 0) d2 = ENC(b1[u1], 0);
          if (o2ones > 1) d3 = ENC(b1[u1 + 1], 0);
        }
      } else {
        const int i = w - w4 - w3 - w2;
        const int basei = u1 + o2ones + 4 * i;
        if (basei + 0 < c1) d0 = ENC(b1[basei + 0], 0);
        if (basei + 1 < c1) d1 = ENC(b1[basei + 1], 0);
        if (basei + 2 < c1) d2 = ENC(b1[basei + 2], 0);
        if (basei + 3 < c1) d3 = ENC(b1[basei + 3], 0);
      }
      int4 v; v.x = d0; v.y = d1; v.z = d2; v.w = d3;
      *(int4*)(wdesc + 4 * w) = v;
    }
#undef ENC
  } else {
    // ---- pack: weights -> frag-ordered bf16, one frag per thread ----
    const int idx = (b - 6145) * 256 + tid;
    if (idx < 2560) {
      const float* Wm;
      int w, s, lane;
      if (idx < 1024) {
        w = idx >> 8; s = (idx >> 6) & 3; lane = idx & 63; Wm = W1_w;
      } else {
        int r = idx - 1024;
        int li = r >> 9;
        w = (r >> 7) & 3; s = (r >> 6) & 1; lane = r & 63;
        Wm = (li == 0) ? W2_w : (li == 1) ? A1_w : A2_w;
      }
      const int g = lane >> 4, c = lane & 15;
#pragma unroll
      for (int j = 0; j < 8; ++j)
        frag_ws[idx * 8 + j] = f2bf(Wm[(32 * s + 8 * g + j) * EE + 16 * w + c]);
    }
  }
}

// ---------------- fused: window GEMM, async staging + LDS ab/po -----------
__global__
__attribute__((amdgpu_flat_work_group_size(256, 256)))
__attribute__((amdgpu_waves_per_eu(4, 4)))
void fused_kernel(const unsigned short* __restrict__ ur_bf,
                  const float* __restrict__ W1_b, const float* __restrict__ W2_b,
                  const float* __restrict__ A2_b,
                  const float* __restrict__ A3_w, const float* __restrict__ A3_b,
                  const float* __restrict__ Ow_w, const float* __restrict__ Ow_b,
                  const int* __restrict__ pu_history,
                  const int* __restrict__ pr_history,
                  const short8* __restrict__ pf,
                  const float* __restrict__ post_ws,
                  const float* __restrict__ abase_ws,
                  const int* __restrict__ wdesc, const int* __restrict__ Wptr,
                  float* __restrict__ out) {
  const int tid = (int)threadIdx.x;
  const int lane = tid & 63;
  const int w = tid >> 6;
  const int g = lane >> 4;
  const int c = lane & 15;

  __shared__ __align__(16) unsigned char xb0[16384];  // X0 (K=128)
  __shared__ __align__(16) unsigned char xb1[8192];   // X1 / X3
  __shared__ __align__(16) unsigned char xb2[8192];   // X2 = o (bf16)
  __shared__ float bias_s[256];                       // b1|b2|A2_b|A3_w
  __shared__ float lpart[4][64];
  __shared__ float att_s[64];
  __shared__ float h_s[4][128];
  __shared__ float ab_s[4][64];                       // abase per slot
  __shared__ float po_s[4][64];                       // post per slot

  // resident per-wave weight frags: 10 short8 = 40 VGPR
  short8 Wf1[4], Wf2[2], Wf3[2], Wf4[2];
#pragma unroll
  for (int s = 0; s < 4; ++s) Wf1[s] = pf[(w * 4 + s) * 64 + lane];
#pragma unroll
  for (int s = 0; s < 2; ++s) {
    Wf2[s] = pf[1024 + (w * 2 + s) * 64 + lane];
    Wf3[s] = pf[1536 + (w * 2 + s) * 64 + lane];
    Wf4[s] = pf[2048 + (w * 2 + s) * 64 + lane];
  }
  if (tid < 64) {
    bias_s[tid]       = W1_b[tid];
    bias_s[64 + tid]  = W2_b[tid];
    bias_s[128 + tid] = A2_b[tid];
    bias_s[192 + tid] = A3_w[tid];
  }

  const float b3 = A3_b[0];
  const float owb = Ow_b[lane];
  const unsigned short* rbase = ur_bf + NUE;
  const int Wtot = *Wptr;
  const int stride = gridDim.x;

  // staging per-lane constants: batch b covers rows b*4 + (lane>>4),
  // linear chunk ch' = lane&15; source chunk chs = ch' ^ (row&7).
  const int r0 = lane >> 4;                 // 0..3
  const int cE = (lane & 15) ^ r0;          // chunk for b = 0, 2
  const int cO = (lane & 15) ^ (r0 + 4);    // chunk for b = 1, 3
  const unsigned short* tabE = ((cE < 8) ? ur_bf : rbase) + (cE & 7) * 8;
  const unsigned short* tabO = ((cO < 8) ? ur_bf : rbase) + (cO & 7) * 8;
  const int* histE = (cE < 8) ? pu_history : pr_history;
  const int* histO = (cO < 8) ? pu_history : pr_history;
  unsigned char* const sbase = xb0 + w * 4096;

  // ---- prologue: stage window blockIdx.x into xb0 (slot w) ----
  if (blockIdx.x < Wtot) {
    const int dn = wdesc[blockIdx.x * 4 + w];
    if (dn >= 0) {
      const int nd = (dn & 0x3FFF) * LL + (((dn >> 14) & 3) << 4);
      const int lim = ((dn >> 16) & 63) - (((dn >> 14) & 3) << 4);
#pragma unroll
      for (int b = 0; b < 4; ++b) {
        const int row = b * 4 + r0;
        const int* hh = (b & 1) ? histO : histE;
        const unsigned short* tt = (b & 1) ? tabO : tabE;
        if (row < lim) {
          const int idx = hh[nd + row];
          gl_lds16(tt + (size_t)idx * EE, sbase + b * 1024);
        }
      }
    }
  }
  __syncthreads();

  for (int wi = blockIdx.x; wi < Wtot; wi += stride) {
    // ---- current-window descriptors (one dwordx4) ----
    const int4 dd = *(const int4*)(wdesc + wi * 4);
    const int d0 = dd.x, d1 = dd.y, d2 = dd.z, d3 = dd.w;
    const int dw = (w == 0) ? d0 : (w == 1) ? d1 : (w == 2) ? d2 : d3;
    const bool fin = (dw >= 0) && (((dw >> 14) & 3) == 0);
    const int fnode = dw & 0x3FFF;
    const int flen = (dw >> 16) & 63;

    // ---- LDS-prefetch abase + post for this window (reg-free) ----
    // prior reads: ab_s in L3 of prev window (>=2 barriers ago), po_s in own
    // finish (program order). Drained at B1; ab used after B2, po after B4.
    if (dw >= 0) {
      gl_lds4(abase_ws + (size_t)fnode * EE + lane, ab_s[w]);
      gl_lds4(post_ws + (size_t)fnode * EE + lane, po_s[w]);
    }

    // ---- prefetch NEXT window's staging indices (hides under L1) ----
    const int win = wi + stride;
    int sidx0 = 0, sidx1 = 0, sidx2 = 0, sidx3 = 0;
    int svmask = 0;
    if (win < Wtot) {
      const int dn = wdesc[win * 4 + w];
      if (dn >= 0) {
        const int nd = (dn & 0x3FFF) * LL + (((dn >> 14) & 3) << 4);
        const int lim = ((dn >> 16) & 63) - (((dn >> 14) & 3) << 4);
        if (r0 + 0  < lim) { sidx0 = histE[nd + r0];      svmask |= 1; }
        if (r0 + 4  < lim) { sidx1 = histO[nd + r0 + 4];  svmask |= 2; }
        if (r0 + 8  < lim) { sidx2 = histE[nd + r0 + 8];  svmask |= 4; }
        if (r0 + 12 < lim) { sidx3 = histO[nd + r0 + 12]; svmask |= 8; }
      }
    }

    f32x4 acc[4];

    // ---- L1: X1 = relu(X0 @ W1 + b1), K=128 ----
    {
      const f32x4 binit = ld4(bias_s + 16 * w + 4 * g);
#pragma unroll
      for (int rt = 0; rt < 4; ++rt) acc[rt] = binit;
#pragma unroll
      for (int s = 0; s < 4; ++s)
#pragma unroll
        for (int rt = 0; rt < 4; ++rt) {
          const int row = rt * 16 + c;
          const short8 bf =
              *(const short8*)(xb0 + SWZ(row, row * 256 + s * 64 + g * 16));
          acc[rt] = MFMA(Wf1[s], bf, acc[rt]);
        }
#pragma unroll
      for (int rt = 0; rt < 4; ++rt) {
        const f32x4 v = relu4(acc[rt]);
        ushort4 p;
        p.x = f2bf(v[0]); p.y = f2bf(v[1]); p.z = f2bf(v[2]); p.w = f2bf(v[3]);
        const int row = rt * 16 + c;
        *(ushort4*)(xb1 + SWZ(row, row * 128 + w * 32 + g * 8)) = p;
      }
    }
    __syncthreads();  // B1: xb1 ready; xb0 FREE; ab/po drained

    // ---- issue async staging of next window into xb0 (reg-free) ----
    if (svmask & 1) gl_lds16(tabE + (size_t)sidx0 * EE, sbase);
    if (svmask & 2) gl_lds16(tabO + (size_t)sidx1 * EE, sbase + 1024);
    if (svmask & 4) gl_lds16(tabE + (size_t)sidx2 * EE, sbase + 2048);
    if (svmask & 8) gl_lds16(tabO + (size_t)sidx3 * EE, sbase + 3072);

    // ---- L2: o = relu(X1 @ W2 + b2) ----
    {
      const f32x4 binit = ld4(bias_s + 64 + 16 * w + 4 * g);
#pragma unroll
      for (int rt = 0; rt < 4; ++rt) acc[rt] = binit;
#pragma unroll
      for (int s = 0; s < 2; ++s)
#pragma unroll
        for (int rt = 0; rt < 4; ++rt) {
          const int row = rt * 16 + c;
          const short8 bf =
              *(const short8*)(xb1 + SWZ(row, row * 128 + s * 64 + g * 16));
          acc[rt] = MFMA(Wf2[s], bf, acc[rt]);
        }
#pragma unroll
      for (int rt = 0; rt < 4; ++rt) {
        const f32x4 v = relu4(acc[rt]);
        ushort4 p;
        p.x = f2bf(v[0]); p.y = f2bf(v[1]); p.z = f2bf(v[2]); p.w = f2bf(v[3]);
        const int row = rt * 16 + c;
        *(ushort4*)(xb2 + SWZ(row, row * 128 + w * 32 + g * 8)) = p;
      }
    }
    __syncthreads();  // B2: xb2 ready; xb0 staging drained (under L2)

    // ---- L3: a1 = relu(o @ A1[0:64] + abase[slot rt]) -> xb1 ----
    {
#pragma unroll
      for (int rt = 0; rt < 4; ++rt)
        acc[rt] = ld4(&ab_s[rt][16 * w + 4 * g]);
#pragma unroll
      for (int s = 0; s < 2; ++s)
#pragma unroll
        for (int rt = 0; rt < 4; ++rt) {
          const int row = rt * 16 + c;
          const short8 bf =
              *(const short8*)(xb2 + SWZ(row, row * 128 + s * 64 + g * 16));
          acc[rt] = MFMA(Wf3[s], bf, acc[rt]);
        }
#pragma unroll
      for (int rt = 0; rt < 4; ++rt) {
        const f32x4 v = relu4(acc[rt]);
        ushort4 p;
        p.x = f2bf(v[0]); p.y = f2bf(v[1]); p.z = f2bf(v[2]); p.w = f2bf(v[3]);
        const int row = rt * 16 + c;
        *(ushort4*)(xb1 + SWZ(row, row * 128 + w * 32 + g * 8)) = p;
      }
    }
    __syncthreads();  // B3

    // ---- L4: a2 = relu(X3 @ A2 + b); logit partials ----
    {
      const f32x4 binit = ld4(bias_s + 128 + 16 * w + 4 * g);
#pragma unroll
      for (int rt = 0; rt < 4; ++rt) acc[rt] = binit;
#pragma unroll
      for (int s = 0; s < 2; ++s)
#pragma unroll
        for (int rt = 0; rt < 4; ++rt) {
          const int row = rt * 16 + c;
          const short8 bf =
              *(const short8*)(xb1 + SWZ(row, row * 128 + s * 64 + g * 16));
          acc[rt] = MFMA(Wf4[s], bf, acc[rt]);
        }
      const f32x4 a3 = ld4(bias_s + 192 + 16 * w + 4 * g);
#pragma unroll
      for (int rt = 0; rt < 4; ++rt) {
        const f32x4 r = relu4(acc[rt]);
        float p = r[0] * a3[0];
        p = fmaf(r[1], a3[1], p);
        p = fmaf(r[2], a3[2], p);
        p = fmaf(r[3], a3[3], p);
        p += __shfl_xor(p, 16);
        p += __shfl_xor(p, 32);
        if (lane < 16) lpart[w][rt * 16 + lane] = p;
      }
    }
    __syncthreads();  // B4: lpart ready; xb1 free

    // ---- finish: wave w owns node with tile0 at slot w ----
    if (fin) {
      const bool vr = (lane < flen);
      float lg = -INFINITY;
      if (vr) {
        const int row = w * 16 + lane;
        lg = lpart[0][row] + lpart[1][row] + lpart[2][row] + lpart[3][row] + b3;
      }
      float mx = lg;
#pragma unroll
      for (int off = 32; off > 0; off >>= 1)
        mx = fmaxf(mx, __shfl_xor(mx, off));
      const float e = __expf(lg - mx);
      float sm = e;
#pragma unroll
      for (int off = 32; off > 0; off >>= 1) sm += __shfl_xor(sm, off);
      if (vr) att_s[w * 16 + lane] = e / sm;

      float h0 = 0.f, h1 = 0.f;
      for (int r2 = 0; r2 + 1 < flen; r2 += 2) {
        const int ra = w * 16 + r2, rb = ra + 1;
        const unsigned short oa =
            *(const unsigned short*)(xb2 + SWZ(ra, ra * 128 + lane * 2));
        const unsigned short ob =
            *(const unsigned short*)(xb2 + SWZ(rb, rb * 128 + lane * 2));
        h0 = fmaf(att_s[ra], bf2f(oa), h0);
        h1 = fmaf(att_s[rb], bf2f(ob), h1);
      }
      if (flen & 1) {
        const int ra = w * 16 + flen - 1;
        const unsigned short oa =
            *(const unsigned short*)(xb2 + SWZ(ra, ra * 128 + lane * 2));
        h0 = fmaf(att_s[ra], bf2f(oa), h0);
      }
      h_s[w][lane] = h0 + h1;
      h_s[w][64 + lane] = po_s[w][lane];

      float s0 = 0.f, s1 = 0.f, s2 = 0.f, s3 = 0.f;
#pragma unroll 8
      for (int k = 0; k < 128; k += 4) {
        s0 = fmaf(h_s[w][k],     Ow_w[(k)     * EE + lane], s0);
        s1 = fmaf(h_s[w][k + 1], Ow_w[(k + 1) * EE + lane], s1);
        s2 = fmaf(h_s[w][k + 2], Ow_w[(k + 2) * EE + lane], s2);
        s3 = fmaf(h_s[w][k + 3], Ow_w[(k + 3) * EE + lane], s3);
      }
      const float a = owb + ((s0 + s1) + (s2 + s3));
      out[(size_t)fnode * EE + lane] = fmaxf(a, 0.f);
    }
    // no trailing barrier: next window's LDS writes are >=1 barrier away
  }
}

// ---------------- R1 fallback (all-f32, no workspace) ----------------
template <int K>
__device__ __forceinline__ void mm2(const float* row0, const float* row1,
                                    const float* __restrict__ W, int e,
                                    float& acc0, float& acc1) {
  const float4* r0 = (const float4*)row0;
  const float4* r1 = (const float4*)row1;
#pragma unroll 4
  for (int k4 = 0; k4 < K / 4; ++k4) {
    float4 va = r0[k4];
    float4 vb = r1[k4];
    const float* w = W + (k4 * 4) * EE + e;
    float w0 = w[0], w1 = w[EE], w2 = w[2 * EE], w3 = w[3 * EE];
    acc0 = fmaf(va.x, w0, acc0);  acc1 = fmaf(vb.x, w0, acc1);
    acc0 = fmaf(va.y, w1, acc0);  acc1 = fmaf(vb.y, w1, acc1);
    acc0 = fmaf(va.z, w2, acc0);  acc1 = fmaf(vb.z, w2, acc1);
    acc0 = fmaf(va.w, w3, acc0);  acc1 = fmaf(vb.w, w3, acc1);
  }
}

__global__ __launch_bounds__(256, 4)
void postenc_kernel(
    const float* __restrict__ u2e, const float* __restrict__ r2e,
    const float* __restrict__ content_emb,
    const float* __restrict__ We_w, const float* __restrict__ We_b,
    const float* __restrict__ W1_w, const float* __restrict__ W1_b,
    const float* __restrict__ W2_w, const float* __restrict__ W2_b,
    const float* __restrict__ A1_w, const float* __restrict__ A1_b,
    const float* __restrict__ A2_w, const float* __restrict__ A2_b,
    const float* __restrict__ A3_w, const float* __restrict__ A3_b,
    const float* __restrict__ Ow_w, const float* __restrict__ Ow_b,
    const int* __restrict__ pu_history, const int* __restrict__ pr_history,
    const int* __restrict__ lengths, const int* __restrict__ pr_content,
    float* __restrict__ out) {
  const int n = blockIdx.x;
  const int tid = (int)threadIdx.x;
  const int e = tid & 63;
  const int g = tid >> 6;

  __shared__ float post_s[EE];
  __shared__ float abase_s[EE];
  __shared__ float in_s[8][128];
  __shared__ float x_s[8][EE];
  __shared__ float a_s[8][EE];
  __shared__ float o_s[56][EE];
  __shared__ float logit_s[EE];
  __shared__ float att_s[EE];
  __shared__ float red_s[4][EE];

  const int len = lengths[n];
  float p = 0.f;

  if (g == 0) {
    const float* ce = content_emb + (size_t)pr_content[n] * 128;
    float acc = We_b[e];
#pragma unroll 4
    for (int k = 0; k < 128; ++k) acc = fmaf(ce[k], We_w[k * EE + e], acc);
    p = fmaxf(acc, 0.f);
    post_s[e] = p;
    float ab = A1_b[e];
#pragma unroll
    for (int k = 0; k < 64; ++k) {
      float pk = __shfl(p, k);
      ab = fmaf(pk, A1_w[(64 + k) * EE + e], ab);
    }
    abase_s[e] = ab;
    logit_s[e] = -INFINITY;
  }
  __syncthreads();

  for (int lb = 0; lb < 56; lb += 8) {
    const int l0 = lb + g;
    const int l1 = l0 + 4;
    const bool v0 = l0 < LL;
    const bool v1 = l1 < LL;

    int pu0 = 0, pr0 = 0, pu1 = 0, pr1 = 0;
    if (v0) { pu0 = pu_history[n * LL + l0]; pr0 = pr_history[n * LL + l0]; }
    if (v1) { pu1 = pu_history[n * LL + l1]; pr1 = pr_history[n * LL + l1]; }
    in_s[g][e]          = v0 ? u2e[(size_t)pu0 * EE + e] : 0.f;
    in_s[g][64 + e]     = v0 ? r2e[pr0 * EE + e]         : 0.f;
    in_s[g + 4][e]      = v1 ? u2e[(size_t)pu1 * EE + e] : 0.f;
    in_s[g + 4][64 + e] = v1 ? r2e[pr1 * EE + e]         : 0.f;
    __syncthreads();

    float acc0 = W1_b[e], acc1 = acc0;
    mm2<128>(in_s[g], in_s[g + 4], W1_w, e, acc0, acc1);
    x_s[g][e]     = fmaxf(acc0, 0.f);
    x_s[g + 4][e] = fmaxf(acc1, 0.f);
    __syncthreads();

    acc0 = W2_b[e]; acc1 = acc0;
    mm2<64>(x_s[g], x_s[g + 4], W2_w, e, acc0, acc1);
    float o0 = fmaxf(acc0, 0.f);
    float o1 = fmaxf(acc1, 0.f);
    if (v0) o_s[l0][e] = o0;
    if (v1) o_s[l1][e] = o1;
    x_s[g][e]     = o0;
    x_s[g + 4][e] = o1;
    __syncthreads();

    acc0 = abase_s[e]; acc1 = acc0;
    mm2<64>(x_s[g], x_s[g + 4], A1_w, e, acc0, acc1);
    a_s[g][e]     = fmaxf(acc0, 0.f);
    a_s[g + 4][e] = fmaxf(acc1, 0.f);
    __syncthreads();

    acc0 = A2_b[e]; acc1 = acc0;
    mm2<64>(a_s[g], a_s[g + 4], A2_w, e, acc0, acc1);
    float w3 = A3_w[e];
    float p0 = fmaxf(acc0, 0.f) * w3;
    float p1 = fmaxf(acc1, 0.f) * w3;
#pragma unroll
    for (int off = 32; off > 0; off >>= 1) {
      p0 += __shfl_xor(p0, off);
      p1 += __shfl_xor(p1, off);
    }
    if (e == 0) {
      float b3 = A3_b[0];
      if (l0 < len) logit_s[l0] = p0 + b3;
      if (l1 < len) logit_s[l1] = p1 + b3;
    }
    __syncthreads();
  }

  if (g == 0) {
    float lg = logit_s[e];
    float m = lg;
#pragma unroll
    for (int off = 32; off > 0; off >>= 1) m = fmaxf(m, __shfl_xor(m, off));
    float pe = __expf(lg - m);
    float sm = pe;
#pragma unroll
    for (int off = 32; off > 0; off >>= 1) sm += __shfl_xor(sm, off);
    att_s[e] = pe / sm;
  }
  __syncthreads();

  {
    const int l_lo = 13 * g;
    const int l_hi = (13 * g + 13 < LL) ? 13 * g + 13 : LL;
    float h = 0.f;
    for (int l = l_lo; l < l_hi; ++l) h = fmaf(att_s[l], o_s[l][e], h);
    red_s[g][e] = h;
  }
  __syncthreads();

  if (g == 0) {
    float h = red_s[0][e] + red_s[1][e] + red_s[2][e] + red_s[3][e];
    float acc = Ow_b[e];
#pragma unroll
    for (int k = 0; k < 64; ++k) {
      float hk = __shfl(h, k);
      acc = fmaf(hk, Ow_w[k * EE + e], acc);
    }
#pragma unroll
    for (int k = 0; k < 64; ++k) {
      float pk = __shfl(p, k);
      acc = fmaf(pk, Ow_w[(64 + k) * EE + e], acc);
    }
    out[(size_t)n * EE + e] = fmaxf(acc, 0.f);
  }
}

// ---------------- launcher ----------------
extern "C" void kernel_launch(void* const* d_in, const int* in_sizes, int n_in,
                              void* d_out, int out_size, void* d_ws, size_t ws_size,
                              hipStream_t stream) {
  const float* u2e         = (const float*)d_in[0];
  const float* r2e         = (const float*)d_in[1];
  const float* content_emb = (const float*)d_in[2];
  const float* We_w = (const float*)d_in[3];
  const float* We_b = (const float*)d_in[4];
  const float* W1_w = (const float*)d_in[5];
  const float* W1_b = (const float*)d_in[6];
  const float* W2_w = (const float*)d_in[7];
  const float* W2_b = (const float*)d_in[8];
  const float* A1_w = (const float*)d_in[9];
  const float* A1_b = (const float*)d_in[10];
  const float* A2_w = (const float*)d_in[11];
  const float* A2_b = (const float*)d_in[12];
  const float* A3_w = (const float*)d_in[13];
  const float* A3_b = (const float*)d_in[14];
  const float* Ow_w = (const float*)d_in[15];
  const float* Ow_b = (const float*)d_in[16];
  // d_in[17] = nodes (unused)
  const int* pu_history = (const int*)d_in[18];
  const int* pr_history = (const int*)d_in[19];
  const int* lengths    = (const int*)d_in[20];
  const int* pr_content = (const int*)d_in[21];
  float* out = (float*)d_out;

  // workspace layout (bytes)
  const size_t FR_OFF  = 0;                               // frags 40960B
  const size_t PO_OFF  = 65536;
  const size_t AB_OFF  = PO_OFF + (size_t)NN * EE * 4;    // +4MB
  const size_t UBF_OFF = AB_OFF + (size_t)NN * EE * 4;    // +4MB
  const size_t CNT_OFF = UBF_OFF + (size_t)(NUE + 384) * 2;
  const size_t BK_OFF  = CNT_OFF + 256;
  const size_t WD_OFF  = BK_OFF + (size_t)4 * NN * 4;
  const size_t NEED    = WD_OFF + (size_t)NN * 4 * 4;     // ~20.8 MB

  if (ws_size < NEED) {
    postenc_kernel<<<NN, 256, 0, stream>>>(
        u2e, r2e, content_emb, We_w, We_b, W1_w, W1_b, W2_w, W2_b,
        A1_w, A1_b, A2_w, A2_b, A3_w, A3_b, Ow_w, Ow_b,
        pu_history, pr_history, lengths, pr_content, out);
    return;
  }

  char* wsp = (char*)d_ws;
  unsigned short* frag_ws = (unsigned short*)(wsp + FR_OFF);
  float* post_ws  = (float*)(wsp + PO_OFF);
  float* abase_ws = (float*)(wsp + AB_OFF);
  unsigned short* ur_bf = (unsigned short*)(wsp + UBF_OFF);
  int* Wout_ws = (int*)(wsp + CNT_OFF);
  int* bk_ws   = (int*)(wsp + BK_OFF);
  int* wd_ws   = (int*)(wsp + WD_OFF);

  pre_kernel<<<6155, 256, 0, stream>>>(
      u2e, r2e, content_emb, pr_content, We_w, We_b, W1_w, W2_w,
      A1_w, A1_b, A2_w, lengths, ur_bf, bk_ws, wd_ws, Wout_ws,
      frag_ws, post_ws, abase_ws);
  fused_kernel<<<2048, 256, 0, stream>>>(
      ur_bf, W1_b, W2_b, A2_b, A3_w, A3_b, Ow_w, Ow_b,
      pu_history, pr_history, (const short8*)frag_ws,
      post_ws, abase_ws, wd_ws, Wout_ws, out);
}

// Round 14
// 206.327 us; speedup vs baseline: 1.0384x; 1.0384x over previous
//
#include <hip/hip_runtime.h>
#include <hip/hip_bf16.h>
#include <math.h>

// PostEncode R14: R12 fused (verbatim, grid 1024, 108us measured) +
// mega-pre with PINNED register budget.
// R13 post-mortem: mega-pre was allocated 16 VGPRs (occupancy heuristic) ->
// conv phase latency-serialized (124us); fused grid 2048 doubled prologue
// staging + gl_lds4 rework hurt (108->124). R14: pre_kernel pinned to
// waves_per_eu(4,4) (128 VGPR) so conv pipelines; fused reverted to R12.

#define NN 16384
#define LL 50
#define EE 64
#define NUE 6400000  // u2e bf16 elements; r2e table follows

typedef __attribute__((ext_vector_type(8))) short short8;
typedef __attribute__((ext_vector_type(4))) float f32x4;

static __device__ __forceinline__ unsigned short f2bf(float x) {
  __hip_bfloat16 h = __float2bfloat16(x);
  unsigned short u;
  __builtin_memcpy(&u, &h, 2);
  return u;
}

static __device__ __forceinline__ float bf2f(unsigned short u) {
  unsigned int v = ((unsigned int)u) << 16;
  float f;
  __builtin_memcpy(&f, &v, 4);
  return f;
}

static __device__ __forceinline__ f32x4 ld4(const float* p) {
  return *(const f32x4*)p;
}

static __device__ __forceinline__ f32x4 relu4(f32x4 a) {
  f32x4 r;
  r[0] = fmaxf(a[0], 0.f); r[1] = fmaxf(a[1], 0.f);
  r[2] = fmaxf(a[2], 0.f); r[3] = fmaxf(a[3], 0.f);
  return r;
}

// async 16B/lane global->LDS; lds dest = wave-uniform base + lane*16
static __device__ __forceinline__ void gl_lds16(const unsigned short* g,
                                                unsigned char* l) {
  __builtin_amdgcn_global_load_lds(
      (const __attribute__((address_space(1))) void*)g,
      (__attribute__((address_space(3))) void*)l, 16, 0, 0);
}

#define MFMA(A, B, C) __builtin_amdgcn_mfma_f32_16x16x32_bf16((A), (B), (C), 0, 0, 0)
#define SWZ(row, byteoff) ((byteoff) ^ (((row) & 7) << 4))

// ---------------- mega-pre: conv | setup | bucket+wdesc | pack ------------
// blocks [0,2048): conv ; [2048,6144): setup (4 nodes/block) ;
// 6144: bucket+wdesc ; [6145,6155): pack.
// dsc encode: node(14) | tile(2)<<14 | len(6)<<16 ; -1 = empty slot.
// waves_per_eu(4,4): pin 128-VGPR budget (R13's 16-VGPR allocation
// latency-serialized the conv phase).
__global__
__attribute__((amdgpu_flat_work_group_size(256, 256)))
__attribute__((amdgpu_waves_per_eu(4, 4)))
void pre_kernel(const float* __restrict__ u2e, const float* __restrict__ r2e,
                const float* __restrict__ content_emb,
                const int* __restrict__ pr_content,
                const float* __restrict__ We_w, const float* __restrict__ We_b,
                const float* __restrict__ W1_w, const float* __restrict__ W2_w,
                const float* __restrict__ A1_w, const float* __restrict__ A1_b,
                const float* __restrict__ A2_w,
                const int* __restrict__ lengths,
                unsigned short* __restrict__ ur_bf,
                int* __restrict__ buckets, int* __restrict__ wdesc,
                int* __restrict__ Wout, unsigned short* __restrict__ frag_ws,
                float* __restrict__ post_ws, float* __restrict__ abase_ws) {
  const int b = blockIdx.x;
  const int tid = (int)threadIdx.x;
  __shared__ float ce_s[4][128];
  __shared__ float post_s[4][64];
  __shared__ int cnt_s[4];

  if (b < 2048) {
    // ---- conv: u2e,r2e f32 -> bf16 tables (BW-bound; needs regs to pipe) ----
    const int total8 = (NUE + 384) / 8;
    for (int i = b * 256 + tid; i < total8; i += 2048 * 256) {
      const long long e0 = (long long)i * 8;
      const float* src = (e0 < NUE) ? (u2e + e0) : (r2e + (e0 - NUE));
      float4 a = *(const float4*)src;
      float4 bb = *(const float4*)(src + 4);
      short8 v;
      v[0] = (short)f2bf(a.x); v[1] = (short)f2bf(a.y);
      v[2] = (short)f2bf(a.z); v[3] = (short)f2bf(a.w);
      v[4] = (short)f2bf(bb.x); v[5] = (short)f2bf(bb.y);
      v[6] = (short)f2bf(bb.z); v[7] = (short)f2bf(bb.w);
      *reinterpret_cast<short8*>(ur_bf + e0) = v;
    }
  } else if (b < 6144) {
    // ---- setup: post + abase, 4 nodes/block ----
    const int sub = tid >> 6;
    const int e = tid & 63;
    const int n = (b - 2048) * 4 + sub;
    const float* ce = content_emb + (size_t)pr_content[n] * 128;
    ce_s[sub][e] = ce[e];
    ce_s[sub][64 + e] = ce[64 + e];
    __syncthreads();
    float acc = We_b[e];
#pragma unroll 8
    for (int k = 0; k < 128; ++k)
      acc = fmaf(ce_s[sub][k], We_w[k * EE + e], acc);
    float po = fmaxf(acc, 0.f);
    post_s[sub][e] = po;
    post_ws[(size_t)n * EE + e] = po;
    __syncthreads();
    float ab = A1_b[e];
#pragma unroll 8
    for (int k = 0; k < 64; ++k)
      ab = fmaf(post_s[sub][k], A1_w[(64 + k) * EE + e], ab);
    abase_ws[(size_t)n * EE + e] = ab;
  } else if (b == 6144) {
    // ---- bucket (ballot-aggregated) + wdesc ----
    const int lanei = tid & 63;
    if (tid < 4) cnt_s[tid] = 0;
    __syncthreads();
    for (int i0 = 0; i0 < NN; i0 += 256) {
      const int n = i0 + tid;
      const int nt = (lengths[n] + 15) >> 4;  // 1..4
#pragma unroll
      for (int bb = 1; bb <= 4; ++bb) {
        const unsigned long long mask = __ballot(nt == bb);
        if (mask) {
          const int leader = __ffsll((long long)mask) - 1;
          int base = 0;
          if (lanei == leader)
            base = atomicAdd(&cnt_s[bb - 1], (int)__popcll(mask));
          base = __shfl(base, leader);
          if (nt == bb) {
            const int rank = __popcll(mask & ((1ull << lanei) - 1ull));
            buckets[(bb - 1) * NN + base + rank] = n;
          }
        }
      }
    }
    __syncthreads();

    const int c1 = cnt_s[0], c2 = cnt_s[1], c3 = cnt_s[2], c4 = cnt_s[3];
    const int u1 = (c1 < c3) ? c1 : c3;
    const int p2 = c2 >> 1, odd2 = c2 & 1;
    const int rem1 = c1 - u1;
    const int o2ones = odd2 ? ((rem1 < 2) ? rem1 : 2) : 0;
    const int rem1b = rem1 - o2ones;
    const int w4 = c4, w3 = c3, w2 = p2 + odd2, w1 = (rem1b + 3) >> 2;
    const int W = w4 + w3 + w2 + w1;
    if (tid == 0) *Wout = W;

    const int* b1 = buckets;
    const int* b2 = buckets + NN;
    const int* b3 = buckets + 2 * NN;
    const int* b4 = buckets + 3 * NN;
#define ENC(n, t) ((n) | ((t) << 14) | (lengths[(n)] << 16))
    for (int w = tid; w < W; w += 256) {
      int d0 = -1, d1 = -1, d2 = -1, d3 = -1;
      if (w < w4) {
        const int n = b4[w];
        d0 = ENC(n, 0); d1 = ENC(n, 1); d2 = ENC(n, 2); d3 = ENC(n, 3);
      } else if (w < w4 + w3) {
        const int i = w - w4;
        const int n = b3[i];
        d0 = ENC(n, 0); d1 = ENC(n, 1); d2 = ENC(n, 2);
        if (i < u1) d3 = ENC(b1[i], 0);
      } else if (w < w4 + w3 + w2) {
        const int i = w - w4 - w3;
        if (i < p2) {
          const int a = b2[2 * i], bbn = b2[2 * i + 1];
          d0 = ENC(a, 0); d1 = ENC(a, 1); d2 = ENC(bbn, 0); d3 = ENC(bbn, 1);
        } else {
          const int a = b2[c2 - 1];
          d0 = ENC(a, 0); d1 = ENC(a, 1);
          if (o2ones > 0) d2 = ENC(b1[u1], 0);
          if (o2ones > 1) d3 = ENC(b1[u1 + 1], 0);
        }
      } else {
        const int i = w - w4 - w3 - w2;
        const int basei = u1 + o2ones + 4 * i;
        if (basei + 0 < c1) d0 = ENC(b1[basei + 0], 0);
        if (basei + 1 < c1) d1 = ENC(b1[basei + 1], 0);
        if (basei + 2 < c1) d2 = ENC(b1[basei + 2], 0);
        if (basei + 3 < c1) d3 = ENC(b1[basei + 3], 0);
      }
      int4 v; v.x = d0; v.y = d1; v.z = d2; v.w = d3;
      *(int4*)(wdesc + 4 * w) = v;
    }
#undef ENC
  } else {
    // ---- pack: weights -> frag-ordered bf16, one frag per thread ----
    const int idx = (b - 6145) * 256 + tid;
    if (idx < 2560) {
      const float* Wm;
      int w, s, lane;
      if (idx < 1024) {
        w = idx >> 8; s = (idx >> 6) & 3; lane = idx & 63; Wm = W1_w;
      } else {
        int r = idx - 1024;
        int li = r >> 9;
        w = (r >> 7) & 3; s = (r >> 6) & 1; lane = r & 63;
        Wm = (li == 0) ? W2_w : (li == 1) ? A1_w : A2_w;
      }
      const int g = lane >> 4, c = lane & 15;
#pragma unroll
      for (int j = 0; j < 8; ++j)
        frag_ws[idx * 8 + j] = f2bf(Wm[(32 * s + 8 * g + j) * EE + 16 * w + c]);
    }
  }
}

// ---------------- fused: window GEMM (R12 verbatim) ----------------
__global__
__attribute__((amdgpu_flat_work_group_size(256, 256)))
__attribute__((amdgpu_waves_per_eu(4, 4)))
void fused_kernel(const unsigned short* __restrict__ ur_bf,
                  const float* __restrict__ W1_b, const float* __restrict__ W2_b,
                  const float* __restrict__ A2_b,
                  const float* __restrict__ A3_w, const float* __restrict__ A3_b,
                  const float* __restrict__ Ow_w, const float* __restrict__ Ow_b,
                  const int* __restrict__ pu_history,
                  const int* __restrict__ pr_history,
                  const short8* __restrict__ pf,
                  const float* __restrict__ post_ws,
                  const float* __restrict__ abase_ws,
                  const int* __restrict__ wdesc, const int* __restrict__ Wptr,
                  float* __restrict__ out) {
  const int tid = (int)threadIdx.x;
  const int lane = tid & 63;
  const int w = tid >> 6;
  const int g = lane >> 4;
  const int c = lane & 15;

  __shared__ __align__(16) unsigned char xb0[16384];  // X0 (K=128)
  __shared__ __align__(16) unsigned char xb1[8192];   // X1 / X3
  __shared__ __align__(16) unsigned char xb2[8192];   // X2 = o (bf16)
  __shared__ float bias_s[256];                       // b1|b2|A2_b|A3_w
  __shared__ float lpart[4][64];
  __shared__ float att_s[64];
  __shared__ float h_s[4][128];

  // resident per-wave weight frags: 10 short8 = 40 VGPR
  short8 Wf1[4], Wf2[2], Wf3[2], Wf4[2];
#pragma unroll
  for (int s = 0; s < 4; ++s) Wf1[s] = pf[(w * 4 + s) * 64 + lane];
#pragma unroll
  for (int s = 0; s < 2; ++s) {
    Wf2[s] = pf[1024 + (w * 2 + s) * 64 + lane];
    Wf3[s] = pf[1536 + (w * 2 + s) * 64 + lane];
    Wf4[s] = pf[2048 + (w * 2 + s) * 64 + lane];
  }
  if (tid < 64) {
    bias_s[tid]       = W1_b[tid];
    bias_s[64 + tid]  = W2_b[tid];
    bias_s[128 + tid] = A2_b[tid];
    bias_s[192 + tid] = A3_w[tid];
  }

  const float b3 = A3_b[0];
  const float owb = Ow_b[lane];
  const unsigned short* rbase = ur_bf + NUE;
  const int Wtot = *Wptr;
  const int stride = gridDim.x;

  // staging per-lane constants: batch b covers rows b*4 + (lane>>4),
  // linear chunk ch' = lane&15; source chunk chs = ch' ^ (row&7).
  const int r0 = lane >> 4;                 // 0..3
  const int cE = (lane & 15) ^ r0;          // chunk for b = 0, 2
  const int cO = (lane & 15) ^ (r0 + 4);    // chunk for b = 1, 3
  const unsigned short* tabE = ((cE < 8) ? ur_bf : rbase) + (cE & 7) * 8;
  const unsigned short* tabO = ((cO < 8) ? ur_bf : rbase) + (cO & 7) * 8;
  const int* histE = (cE < 8) ? pu_history : pr_history;
  const int* histO = (cO < 8) ? pu_history : pr_history;
  unsigned char* const sbase = xb0 + w * 4096;

  // ---- prologue: stage window blockIdx.x into xb0 (slot w) ----
  if (blockIdx.x < Wtot) {
    const int dn = wdesc[blockIdx.x * 4 + w];
    if (dn >= 0) {
      const int nd = (dn & 0x3FFF) * LL + (((dn >> 14) & 3) << 4);
      const int lim = ((dn >> 16) & 63) - (((dn >> 14) & 3) << 4);
#pragma unroll
      for (int b = 0; b < 4; ++b) {
        const int row = b * 4 + r0;
        const int* hh = (b & 1) ? histO : histE;
        const unsigned short* tt = (b & 1) ? tabO : tabE;
        if (row < lim) {
          const int idx = hh[nd + row];
          gl_lds16(tt + (size_t)idx * EE, sbase + b * 1024);
        }
      }
    }
  }
  __syncthreads();

  for (int wi = blockIdx.x; wi < Wtot; wi += stride) {
    // current-window descriptors (broadcast loads, L2-hot)
    const int d0 = wdesc[wi * 4 + 0];
    const int d1 = wdesc[wi * 4 + 1];
    const int d2 = wdesc[wi * 4 + 2];
    const int d3 = wdesc[wi * 4 + 3];

    // ---- prefetch NEXT window's staging indices (hides under L1) ----
    const int win = wi + stride;
    int sidx0 = 0, sidx1 = 0, sidx2 = 0, sidx3 = 0;
    int svmask = 0;
    if (win < Wtot) {
      const int dn = wdesc[win * 4 + w];
      if (dn >= 0) {
        const int nd = (dn & 0x3FFF) * LL + (((dn >> 14) & 3) << 4);
        const int lim = ((dn >> 16) & 63) - (((dn >> 14) & 3) << 4);
        if (r0 + 0  < lim) { sidx0 = histE[nd + r0];      svmask |= 1; }
        if (r0 + 4  < lim) { sidx1 = histO[nd + r0 + 4];  svmask |= 2; }
        if (r0 + 8  < lim) { sidx2 = histE[nd + r0 + 8];  svmask |= 4; }
        if (r0 + 12 < lim) { sidx3 = histO[nd + r0 + 12]; svmask |= 8; }
      }
    }

    f32x4 acc[4];

    // ---- L1: X1 = relu(X0 @ W1 + b1), K=128 ----
    {
      const f32x4 binit = ld4(bias_s + 16 * w + 4 * g);
#pragma unroll
      for (int rt = 0; rt < 4; ++rt) acc[rt] = binit;
#pragma unroll
      for (int s = 0; s < 4; ++s)
#pragma unroll
        for (int rt = 0; rt < 4; ++rt) {
          const int row = rt * 16 + c;
          const short8 bf =
              *(const short8*)(xb0 + SWZ(row, row * 256 + s * 64 + g * 16));
          acc[rt] = MFMA(Wf1[s], bf, acc[rt]);
        }
#pragma unroll
      for (int rt = 0; rt < 4; ++rt) {
        const f32x4 v = relu4(acc[rt]);
        ushort4 p;
        p.x = f2bf(v[0]); p.y = f2bf(v[1]); p.z = f2bf(v[2]); p.w = f2bf(v[3]);
        const int row = rt * 16 + c;
        *(ushort4*)(xb1 + SWZ(row, row * 128 + w * 32 + g * 8)) = p;
      }
    }
    __syncthreads();  // B1: xb1 ready; xb0 FREE

    // ---- issue async staging of next window into xb0 (reg-free) ----
    if (svmask & 1) gl_lds16(tabE + (size_t)sidx0 * EE, sbase);
    if (svmask & 2) gl_lds16(tabO + (size_t)sidx1 * EE, sbase + 1024);
    if (svmask & 4) gl_lds16(tabE + (size_t)sidx2 * EE, sbase + 2048);
    if (svmask & 8) gl_lds16(tabO + (size_t)sidx3 * EE, sbase + 3072);

    // ---- L2: o = relu(X1 @ W2 + b2) ----
    {
      const f32x4 binit = ld4(bias_s + 64 + 16 * w + 4 * g);
#pragma unroll
      for (int rt = 0; rt < 4; ++rt) acc[rt] = binit;
#pragma unroll
      for (int s = 0; s < 2; ++s)
#pragma unroll
        for (int rt = 0; rt < 4; ++rt) {
          const int row = rt * 16 + c;
          const short8 bf =
              *(const short8*)(xb1 + SWZ(row, row * 128 + s * 64 + g * 16));
          acc[rt] = MFMA(Wf2[s], bf, acc[rt]);
        }
#pragma unroll
      for (int rt = 0; rt < 4; ++rt) {
        const f32x4 v = relu4(acc[rt]);
        ushort4 p;
        p.x = f2bf(v[0]); p.y = f2bf(v[1]); p.z = f2bf(v[2]); p.w = f2bf(v[3]);
        const int row = rt * 16 + c;
        *(ushort4*)(xb2 + SWZ(row, row * 128 + w * 32 + g * 8)) = p;
      }
    }
    __syncthreads();  // B2: xb2 ready; staging drained here (under L2)

    // ---- L3: a1 = relu(o @ A1[0:64] + abase[node(rt)]) -> xb1 ----
    {
      {
        const int n0 = (d0 >= 0) ? (d0 & 0x3FFF) : 0;
        const int n1 = (d1 >= 0) ? (d1 & 0x3FFF) : 0;
        const int n2 = (d2 >= 0) ? (d2 & 0x3FFF) : 0;
        const int n3 = (d3 >= 0) ? (d3 & 0x3FFF) : 0;
        acc[0] = ld4(abase_ws + (size_t)n0 * EE + 16 * w + 4 * g);
        acc[1] = ld4(abase_ws + (size_t)n1 * EE + 16 * w + 4 * g);
        acc[2] = ld4(abase_ws + (size_t)n2 * EE + 16 * w + 4 * g);
        acc[3] = ld4(abase_ws + (size_t)n3 * EE + 16 * w + 4 * g);
      }
#pragma unroll
      for (int s = 0; s < 2; ++s)
#pragma unroll
        for (int rt = 0; rt < 4; ++rt) {
          const int row = rt * 16 + c;
          const short8 bf =
              *(const short8*)(xb2 + SWZ(row, row * 128 + s * 64 + g * 16));
          acc[rt] = MFMA(Wf3[s], bf, acc[rt]);
        }
#pragma unroll
      for (int rt = 0; rt < 4; ++rt) {
        const f32x4 v = relu4(acc[rt]);
        ushort4 p;
        p.x = f2bf(v[0]); p.y = f2bf(v[1]); p.z = f2bf(v[2]); p.w = f2bf(v[3]);
        const int row = rt * 16 + c;
        *(ushort4*)(xb1 + SWZ(row, row * 128 + w * 32 + g * 8)) = p;
      }
    }
    __syncthreads();  // B3

    // ---- L4: a2 = relu(X3 @ A2 + b); logit partials ----
    {
      const f32x4 binit = ld4(bias_s + 128 + 16 * w + 4 * g);
#pragma unroll
      for (int rt = 0; rt < 4; ++rt) acc[rt] = binit;
#pragma unroll
      for (int s = 0; s < 2; ++s)
#pragma unroll
        for (int rt = 0; rt < 4; ++rt) {
          const int row = rt * 16 + c;
          const short8 bf =
              *(const short8*)(xb1 + SWZ(row, row * 128 + s * 64 + g * 16));
          acc[rt] = MFMA(Wf4[s], bf, acc[rt]);
        }
      const f32x4 a3 = ld4(bias_s + 192 + 16 * w + 4 * g);
#pragma unroll
      for (int rt = 0; rt < 4; ++rt) {
        const f32x4 r = relu4(acc[rt]);
        float p = r[0] * a3[0];
        p = fmaf(r[1], a3[1], p);
        p = fmaf(r[2], a3[2], p);
        p = fmaf(r[3], a3[3], p);
        p += __shfl_xor(p, 16);
        p += __shfl_xor(p, 32);
        if (lane < 16) lpart[w][rt * 16 + lane] = p;
      }
    }
    __syncthreads();  // B4: lpart ready; xb1 free

    // ---- finish: wave w owns node with tile0 at slot w ----
    {
      const int dw = (w == 0) ? d0 : (w == 1) ? d1 : (w == 2) ? d2 : d3;
      if (dw >= 0 && ((dw >> 14) & 3) == 0) {
        const int fnode = dw & 0x3FFF;
        const int flen = (dw >> 16) & 63;
        const bool vr = (lane < flen);
        float lg = -INFINITY;
        if (vr) {
          const int row = w * 16 + lane;
          lg = lpart[0][row] + lpart[1][row] + lpart[2][row] + lpart[3][row] + b3;
        }
        float mx = lg;
#pragma unroll
        for (int off = 32; off > 0; off >>= 1)
          mx = fmaxf(mx, __shfl_xor(mx, off));
        const float e = __expf(lg - mx);
        float sm = e;
#pragma unroll
        for (int off = 32; off > 0; off >>= 1) sm += __shfl_xor(sm, off);
        if (vr) att_s[w * 16 + lane] = e / sm;

        float h0 = 0.f, h1 = 0.f;
        for (int r2 = 0; r2 + 1 < flen; r2 += 2) {
          const int ra = w * 16 + r2, rb = ra + 1;
          const unsigned short oa =
              *(const unsigned short*)(xb2 + SWZ(ra, ra * 128 + lane * 2));
          const unsigned short ob =
              *(const unsigned short*)(xb2 + SWZ(rb, rb * 128 + lane * 2));
          h0 = fmaf(att_s[ra], bf2f(oa), h0);
          h1 = fmaf(att_s[rb], bf2f(ob), h1);
        }
        if (flen & 1) {
          const int ra = w * 16 + flen - 1;
          const unsigned short oa =
              *(const unsigned short*)(xb2 + SWZ(ra, ra * 128 + lane * 2));
          h0 = fmaf(att_s[ra], bf2f(oa), h0);
        }
        h_s[w][lane] = h0 + h1;
        h_s[w][64 + lane] = post_ws[(size_t)fnode * EE + lane];

        float s0 = 0.f, s1 = 0.f, s2 = 0.f, s3 = 0.f;
#pragma unroll 8
        for (int k = 0; k < 128; k += 4) {
          s0 = fmaf(h_s[w][k],     Ow_w[(k)     * EE + lane], s0);
          s1 = fmaf(h_s[w][k + 1], Ow_w[(k + 1) * EE + lane], s1);
          s2 = fmaf(h_s[w][k + 2], Ow_w[(k + 2) * EE + lane], s2);
          s3 = fmaf(h_s[w][k + 3], Ow_w[(k + 3) * EE + lane], s3);
        }
        const float a = owb + ((s0 + s1) + (s2 + s3));
        out[(size_t)fnode * EE + lane] = fmaxf(a, 0.f);
      }
    }
    // NO barrier here: next window's first xb2/lpart/att_s writes are >=1
    // full barrier away (L2 after B1; L4 after B3); xb0 staging drained at B2.
  }
}

// ---------------- R1 fallback (all-f32, no workspace) ----------------
template <int K>
__device__ __forceinline__ void mm2(const float* row0, const float* row1,
                                    const float* __restrict__ W, int e,
                                    float& acc0, float& acc1) {
  const float4* r0 = (const float4*)row0;
  const float4* r1 = (const float4*)row1;
#pragma unroll 4
  for (int k4 = 0; k4 < K / 4; ++k4) {
    float4 va = r0[k4];
    float4 vb = r1[k4];
    const float* w = W + (k4 * 4) * EE + e;
    float w0 = w[0], w1 = w[EE], w2 = w[2 * EE], w3 = w[3 * EE];
    acc0 = fmaf(va.x, w0, acc0);  acc1 = fmaf(vb.x, w0, acc1);
    acc0 = fmaf(va.y, w1, acc0);  acc1 = fmaf(vb.y, w1, acc1);
    acc0 = fmaf(va.z, w2, acc0);  acc1 = fmaf(vb.z, w2, acc1);
    acc0 = fmaf(va.w, w3, acc0);  acc1 = fmaf(vb.w, w3, acc1);
  }
}

__global__ __launch_bounds__(256, 4)
void postenc_kernel(
    const float* __restrict__ u2e, const float* __restrict__ r2e,
    const float* __restrict__ content_emb,
    const float* __restrict__ We_w, const float* __restrict__ We_b,
    const float* __restrict__ W1_w, const float* __restrict__ W1_b,
    const float* __restrict__ W2_w, const float* __restrict__ W2_b,
    const float* __restrict__ A1_w, const float* __restrict__ A1_b,
    const float* __restrict__ A2_w, const float* __restrict__ A2_b,
    const float* __restrict__ A3_w, const float* __restrict__ A3_b,
    const float* __restrict__ Ow_w, const float* __restrict__ Ow_b,
    const int* __restrict__ pu_history, const int* __restrict__ pr_history,
    const int* __restrict__ lengths, const int* __restrict__ pr_content,
    float* __restrict__ out) {
  const int n = blockIdx.x;
  const int tid = (int)threadIdx.x;
  const int e = tid & 63;
  const int g = tid >> 6;

  __shared__ float post_s[EE];
  __shared__ float abase_s[EE];
  __shared__ float in_s[8][128];
  __shared__ float x_s[8][EE];
  __shared__ float a_s[8][EE];
  __shared__ float o_s[56][EE];
  __shared__ float logit_s[EE];
  __shared__ float att_s[EE];
  __shared__ float red_s[4][EE];

  const int len = lengths[n];
  float p = 0.f;

  if (g == 0) {
    const float* ce = content_emb + (size_t)pr_content[n] * 128;
    float acc = We_b[e];
#pragma unroll 4
    for (int k = 0; k < 128; ++k) acc = fmaf(ce[k], We_w[k * EE + e], acc);
    p = fmaxf(acc, 0.f);
    post_s[e] = p;
    float ab = A1_b[e];
#pragma unroll
    for (int k = 0; k < 64; ++k) {
      float pk = __shfl(p, k);
      ab = fmaf(pk, A1_w[(64 + k) * EE + e], ab);
    }
    abase_s[e] = ab;
    logit_s[e] = -INFINITY;
  }
  __syncthreads();

  for (int lb = 0; lb < 56; lb += 8) {
    const int l0 = lb + g;
    const int l1 = l0 + 4;
    const bool v0 = l0 < LL;
    const bool v1 = l1 < LL;

    int pu0 = 0, pr0 = 0, pu1 = 0, pr1 = 0;
    if (v0) { pu0 = pu_history[n * LL + l0]; pr0 = pr_history[n * LL + l0]; }
    if (v1) { pu1 = pu_history[n * LL + l1]; pr1 = pr_history[n * LL + l1]; }
    in_s[g][e]          = v0 ? u2e[(size_t)pu0 * EE + e] : 0.f;
    in_s[g][64 + e]     = v0 ? r2e[pr0 * EE + e]         : 0.f;
    in_s[g + 4][e]      = v1 ? u2e[(size_t)pu1 * EE + e] : 0.f;
    in_s[g + 4][64 + e] = v1 ? r2e[pr1 * EE + e]         : 0.f;
    __syncthreads();

    float acc0 = W1_b[e], acc1 = acc0;
    mm2<128>(in_s[g], in_s[g + 4], W1_w, e, acc0, acc1);
    x_s[g][e]     = fmaxf(acc0, 0.f);
    x_s[g + 4][e] = fmaxf(acc1, 0.f);
    __syncthreads();

    acc0 = W2_b[e]; acc1 = acc0;
    mm2<64>(x_s[g], x_s[g + 4], W2_w, e, acc0, acc1);
    float o0 = fmaxf(acc0, 0.f);
    float o1 = fmaxf(acc1, 0.f);
    if (v0) o_s[l0][e] = o0;
    if (v1) o_s[l1][e] = o1;
    x_s[g][e]     = o0;
    x_s[g + 4][e] = o1;
    __syncthreads();

    acc0 = abase_s[e]; acc1 = acc0;
    mm2<64>(x_s[g], x_s[g + 4], A1_w, e, acc0, acc1);
    a_s[g][e]     = fmaxf(acc0, 0.f);
    a_s[g + 4][e] = fmaxf(acc1, 0.f);
    __syncthreads();

    acc0 = A2_b[e]; acc1 = acc0;
    mm2<64>(a_s[g], a_s[g + 4], A2_w, e, acc0, acc1);
    float w3 = A3_w[e];
    float p0 = fmaxf(acc0, 0.f) * w3;
    float p1 = fmaxf(acc1, 0.f) * w3;
#pragma unroll
    for (int off = 32; off > 0; off >>= 1) {
      p0 += __shfl_xor(p0, off);
      p1 += __shfl_xor(p1, off);
    }
    if (e == 0) {
      float b3 = A3_b[0];
      if (l0 < len) logit_s[l0] = p0 + b3;
      if (l1 < len) logit_s[l1] = p1 + b3;
    }
    __syncthreads();
  }

  if (g == 0) {
    float lg = logit_s[e];
    float m = lg;
#pragma unroll
    for (int off = 32; off > 0; off >>= 1) m = fmaxf(m, __shfl_xor(m, off));
    float pe = __expf(lg - m);
    float sm = pe;
#pragma unroll
    for (int off = 32; off > 0; off >>= 1) sm += __shfl_xor(sm, off);
    att_s[e] = pe / sm;
  }
  __syncthreads();

  {
    const int l_lo = 13 * g;
    const int l_hi = (13 * g + 13 < LL) ? 13 * g + 13 : LL;
    float h = 0.f;
    for (int l = l_lo; l < l_hi; ++l) h = fmaf(att_s[l], o_s[l][e], h);
    red_s[g][e] = h;
  }
  __syncthreads();

  if (g == 0) {
    float h = red_s[0][e] + red_s[1][e] + red_s[2][e] + red_s[3][e];
    float acc = Ow_b[e];
#pragma unroll
    for (int k = 0; k < 64; ++k) {
      float hk = __shfl(h, k);
      acc = fmaf(hk, Ow_w[k * EE + e], acc);
    }
#pragma unroll
    for (int k = 0; k < 64; ++k) {
      float pk = __shfl(p, k);
      acc = fmaf(pk, Ow_w[(64 + k) * EE + e], acc);
    }
    out[(size_t)n * EE + e] = fmaxf(acc, 0.f);
  }
}

// ---------------- launcher ----------------
extern "C" void kernel_launch(void* const* d_in, const int* in_sizes, int n_in,
                              void* d_out, int out_size, void* d_ws, size_t ws_size,
                              hipStream_t stream) {
  const float* u2e         = (const float*)d_in[0];
  const float* r2e         = (const float*)d_in[1];
  const float* content_emb = (const float*)d_in[2];
  const float* We_w = (const float*)d_in[3];
  const float* We_b = (const float*)d_in[4];
  const float* W1_w = (const float*)d_in[5];
  const float* W1_b = (const float*)d_in[6];
  const float* W2_w = (const float*)d_in[7];
  const float* W2_b = (const float*)d_in[8];
  const float* A1_w = (const float*)d_in[9];
  const float* A1_b = (const float*)d_in[10];
  const float* A2_w = (const float*)d_in[11];
  const float* A2_b = (const float*)d_in[12];
  const float* A3_w = (const float*)d_in[13];
  const float* A3_b = (const float*)d_in[14];
  const float* Ow_w = (const float*)d_in[15];
  const float* Ow_b = (const float*)d_in[16];
  // d_in[17] = nodes (unused)
  const int* pu_history = (const int*)d_in[18];
  const int* pr_history = (const int*)d_in[19];
  const int* lengths    = (const int*)d_in[20];
  const int* pr_content = (const int*)d_in[21];
  float* out = (float*)d_out;

  // workspace layout (bytes)
  const size_t FR_OFF  = 0;                               // frags 40960B
  const size_t PO_OFF  = 65536;
  const size_t AB_OFF  = PO_OFF + (size_t)NN * EE * 4;    // +4MB
  const size_t UBF_OFF = AB_OFF + (size_t)NN * EE * 4;    // +4MB
  const size_t CNT_OFF = UBF_OFF + (size_t)(NUE + 384) * 2;
  const size_t BK_OFF  = CNT_OFF + 256;
  const size_t WD_OFF  = BK_OFF + (size_t)4 * NN * 4;
  const size_t NEED    = WD_OFF + (size_t)NN * 4 * 4;     // ~20.8 MB

  if (ws_size < NEED) {
    postenc_kernel<<<NN, 256, 0, stream>>>(
        u2e, r2e, content_emb, We_w, We_b, W1_w, W1_b, W2_w, W2_b,
        A1_w, A1_b, A2_w, A2_b, A3_w, A3_b, Ow_w, Ow_b,
        pu_history, pr_history, lengths, pr_content, out);
    return;
  }

  char* wsp = (char*)d_ws;
  unsigned short* frag_ws = (unsigned short*)(wsp + FR_OFF);
  float* post_ws  = (float*)(wsp + PO_OFF);
  float* abase_ws = (float*)(wsp + AB_OFF);
  unsigned short* ur_bf = (unsigned short*)(wsp + UBF_OFF);
  int* Wout_ws = (int*)(wsp + CNT_OFF);
  int* bk_ws   = (int*)(wsp + BK_OFF);
  int* wd_ws   = (int*)(wsp + WD_OFF);

  pre_kernel<<<6155, 256, 0, stream>>>(
      u2e, r2e, content_emb, pr_content, We_w, We_b, W1_w, W2_w,
      A1_w, A1_b, A2_w, lengths, ur_bf, bk_ws, wd_ws, Wout_ws,
      frag_ws, post_ws, abase_ws);
  fused_kernel<<<1024, 256, 0, stream>>>(
      ur_bf, W1_b, W2_b, A2_b, A3_w, A3_b, Ow_w, Ow_b,
      pu_history, pr_history, (const short8*)frag_ws,
      post_ws, abase_ws, wd_ws, Wout_ws, out);
}

// Round 15
// 137.096 us; speedup vs baseline: 1.5628x; 1.5050x over previous
//
#include <hip/hip_runtime.h>
#include <hip/hip_bf16.h>
#include <math.h>

// PostEncode R15: R12 fused (verbatim, 108us measured) + mega-pre reworked.
// R14 post-mortem: pre's tail = single aux block (bucket+wdesc) cut from
// 1024->256 threads in the merge AND dispatched late (block 6144). R15:
//  - pre uses 1024-thread blocks; aux = block 0 (dispatched first, overlaps
//    under conv/setup); conv [1,513); setup [513,1537) 16 nodes/blk;
//    pack [1537,1540)
//  - bucket entries carry len (n | len<<14) -> wdesc ENC is pure ALU
//    (removes the dependent lengths[] load chain)
// dsc encode: node(14) | tile(2)<<14 | len(6)<<16 ; -1 = empty slot.

#define NN 16384
#define LL 50
#define EE 64
#define NUE 6400000  // u2e bf16 elements; r2e table follows

typedef __attribute__((ext_vector_type(8))) short short8;
typedef __attribute__((ext_vector_type(4))) float f32x4;

static __device__ __forceinline__ unsigned short f2bf(float x) {
  __hip_bfloat16 h = __float2bfloat16(x);
  unsigned short u;
  __builtin_memcpy(&u, &h, 2);
  return u;
}

static __device__ __forceinline__ float bf2f(unsigned short u) {
  unsigned int v = ((unsigned int)u) << 16;
  float f;
  __builtin_memcpy(&f, &v, 4);
  return f;
}

static __device__ __forceinline__ f32x4 ld4(const float* p) {
  return *(const f32x4*)p;
}

static __device__ __forceinline__ f32x4 relu4(f32x4 a) {
  f32x4 r;
  r[0] = fmaxf(a[0], 0.f); r[1] = fmaxf(a[1], 0.f);
  r[2] = fmaxf(a[2], 0.f); r[3] = fmaxf(a[3], 0.f);
  return r;
}

// async 16B/lane global->LDS; lds dest = wave-uniform base + lane*16
static __device__ __forceinline__ void gl_lds16(const unsigned short* g,
                                                unsigned char* l) {
  __builtin_amdgcn_global_load_lds(
      (const __attribute__((address_space(1))) void*)g,
      (__attribute__((address_space(3))) void*)l, 16, 0, 0);
}

#define MFMA(A, B, C) __builtin_amdgcn_mfma_f32_16x16x32_bf16((A), (B), (C), 0, 0, 0)
#define SWZ(row, byteoff) ((byteoff) ^ (((row) & 7) << 4))

// ---------------- mega-pre (1024-thr blocks, grid 1540) ----------------
// block 0: bucket+wdesc ; [1,513): conv ; [513,1537): setup ; [1537,1540): pack
__global__ __launch_bounds__(1024)
void pre_kernel(const float* __restrict__ u2e, const float* __restrict__ r2e,
                const float* __restrict__ content_emb,
                const int* __restrict__ pr_content,
                const float* __restrict__ We_w, const float* __restrict__ We_b,
                const float* __restrict__ W1_w, const float* __restrict__ W2_w,
                const float* __restrict__ A1_w, const float* __restrict__ A1_b,
                const float* __restrict__ A2_w,
                const int* __restrict__ lengths,
                unsigned short* __restrict__ ur_bf,
                int* __restrict__ buckets, int* __restrict__ wdesc,
                int* __restrict__ Wout, unsigned short* __restrict__ frag_ws,
                float* __restrict__ post_ws, float* __restrict__ abase_ws) {
  const int b = blockIdx.x;
  const int tid = (int)threadIdx.x;
  __shared__ float ce_s[16][128];
  __shared__ float post_s[16][64];
  __shared__ int cnt_s[4];

  if (b == 0) {
    // ---- bucket (ballot-aggregated, 16 waves) + wdesc ----
    const int lanei = tid & 63;
    if (tid < 4) cnt_s[tid] = 0;
    __syncthreads();
    for (int i0 = 0; i0 < NN; i0 += 1024) {
      const int n = i0 + tid;
      const int ln = lengths[n];
      const int nt = (ln + 15) >> 4;  // 1..4
      const int entry = n | (ln << 14);
#pragma unroll
      for (int bb = 1; bb <= 4; ++bb) {
        const unsigned long long mask = __ballot(nt == bb);
        if (mask) {
          const int leader = __ffsll((long long)mask) - 1;
          int base = 0;
          if (lanei == leader)
            base = atomicAdd(&cnt_s[bb - 1], (int)__popcll(mask));
          base = __shfl(base, leader);
          if (nt == bb) {
            const int rank = __popcll(mask & ((1ull << lanei) - 1ull));
            buckets[(bb - 1) * NN + base + rank] = entry;
          }
        }
      }
    }
    __syncthreads();

    const int c1 = cnt_s[0], c2 = cnt_s[1], c3 = cnt_s[2], c4 = cnt_s[3];
    const int u1 = (c1 < c3) ? c1 : c3;
    const int p2 = c2 >> 1, odd2 = c2 & 1;
    const int rem1 = c1 - u1;
    const int o2ones = odd2 ? ((rem1 < 2) ? rem1 : 2) : 0;
    const int rem1b = rem1 - o2ones;
    const int w4 = c4, w3 = c3, w2 = p2 + odd2, w1 = (rem1b + 3) >> 2;
    const int W = w4 + w3 + w2 + w1;
    if (tid == 0) *Wout = W;

    const int* b1 = buckets;
    const int* b2 = buckets + NN;
    const int* b3 = buckets + 2 * NN;
    const int* b4 = buckets + 3 * NN;
    // entry e = n | len<<14 ; dsc = node | tile<<14 | len<<16 (pure ALU)
#define ENC(e, t) (((e) & 0x3FFF) | ((t) << 14) | (((e) >> 14) << 16))
    for (int w = tid; w < W; w += 1024) {
      int d0 = -1, d1 = -1, d2 = -1, d3 = -1;
      if (w < w4) {
        const int e = b4[w];
        d0 = ENC(e, 0); d1 = ENC(e, 1); d2 = ENC(e, 2); d3 = ENC(e, 3);
      } else if (w < w4 + w3) {
        const int i = w - w4;
        const int e = b3[i];
        d0 = ENC(e, 0); d1 = ENC(e, 1); d2 = ENC(e, 2);
        if (i < u1) d3 = ENC(b1[i], 0);
      } else if (w < w4 + w3 + w2) {
        const int i = w - w4 - w3;
        if (i < p2) {
          const int ea = b2[2 * i], eb = b2[2 * i + 1];
          d0 = ENC(ea, 0); d1 = ENC(ea, 1); d2 = ENC(eb, 0); d3 = ENC(eb, 1);
        } else {
          const int ea = b2[c2 - 1];
          d0 = ENC(ea, 0); d1 = ENC(ea, 1);
          if (o2ones > 0) d2 = ENC(b1[u1], 0);
          if (o2ones > 1) d3 = ENC(b1[u1 + 1], 0);
        }
      } else {
        const int i = w - w4 - w3 - w2;
        const int basei = u1 + o2ones + 4 * i;
        if (basei + 0 < c1) d0 = ENC(b1[basei + 0], 0);
        if (basei + 1 < c1) d1 = ENC(b1[basei + 1], 0);
        if (basei + 2 < c1) d2 = ENC(b1[basei + 2], 0);
        if (basei + 3 < c1) d3 = ENC(b1[basei + 3], 0);
      }
      int4 v; v.x = d0; v.y = d1; v.z = d2; v.w = d3;
      *(int4*)(wdesc + 4 * w) = v;
    }
#undef ENC
  } else if (b < 513) {
    // ---- conv: u2e,r2e f32 -> bf16 tables ----
    const int total8 = (NUE + 384) / 8;
    for (int i = (b - 1) * 1024 + tid; i < total8; i += 512 * 1024) {
      const long long e0 = (long long)i * 8;
      const float* src = (e0 < NUE) ? (u2e + e0) : (r2e + (e0 - NUE));
      float4 a = *(const float4*)src;
      float4 bb = *(const float4*)(src + 4);
      short8 v;
      v[0] = (short)f2bf(a.x); v[1] = (short)f2bf(a.y);
      v[2] = (short)f2bf(a.z); v[3] = (short)f2bf(a.w);
      v[4] = (short)f2bf(bb.x); v[5] = (short)f2bf(bb.y);
      v[6] = (short)f2bf(bb.z); v[7] = (short)f2bf(bb.w);
      *reinterpret_cast<short8*>(ur_bf + e0) = v;
    }
  } else if (b < 1537) {
    // ---- setup: post + abase, 16 nodes/block ----
    const int sub = tid >> 6;
    const int e = tid & 63;
    const int n = (b - 513) * 16 + sub;
    const float* ce = content_emb + (size_t)pr_content[n] * 128;
    ce_s[sub][e] = ce[e];
    ce_s[sub][64 + e] = ce[64 + e];
    __syncthreads();
    float acc = We_b[e];
#pragma unroll 8
    for (int k = 0; k < 128; ++k)
      acc = fmaf(ce_s[sub][k], We_w[k * EE + e], acc);
    float po = fmaxf(acc, 0.f);
    post_s[sub][e] = po;
    post_ws[(size_t)n * EE + e] = po;
    __syncthreads();
    float ab = A1_b[e];
#pragma unroll 8
    for (int k = 0; k < 64; ++k)
      ab = fmaf(post_s[sub][k], A1_w[(64 + k) * EE + e], ab);
    abase_ws[(size_t)n * EE + e] = ab;
  } else {
    // ---- pack: weights -> frag-ordered bf16, one frag per thread ----
    const int idx = (b - 1537) * 1024 + tid;
    if (idx < 2560) {
      const float* Wm;
      int w, s, lane;
      if (idx < 1024) {
        w = idx >> 8; s = (idx >> 6) & 3; lane = idx & 63; Wm = W1_w;
      } else {
        int r = idx - 1024;
        int li = r >> 9;
        w = (r >> 7) & 3; s = (r >> 6) & 1; lane = r & 63;
        Wm = (li == 0) ? W2_w : (li == 1) ? A1_w : A2_w;
      }
      const int g = lane >> 4, c = lane & 15;
#pragma unroll
      for (int j = 0; j < 8; ++j)
        frag_ws[idx * 8 + j] = f2bf(Wm[(32 * s + 8 * g + j) * EE + 16 * w + c]);
    }
  }
}

// ---------------- fused: window GEMM (R12 verbatim) ----------------
__global__
__attribute__((amdgpu_flat_work_group_size(256, 256)))
__attribute__((amdgpu_waves_per_eu(4, 4)))
void fused_kernel(const unsigned short* __restrict__ ur_bf,
                  const float* __restrict__ W1_b, const float* __restrict__ W2_b,
                  const float* __restrict__ A2_b,
                  const float* __restrict__ A3_w, const float* __restrict__ A3_b,
                  const float* __restrict__ Ow_w, const float* __restrict__ Ow_b,
                  const int* __restrict__ pu_history,
                  const int* __restrict__ pr_history,
                  const short8* __restrict__ pf,
                  const float* __restrict__ post_ws,
                  const float* __restrict__ abase_ws,
                  const int* __restrict__ wdesc, const int* __restrict__ Wptr,
                  float* __restrict__ out) {
  const int tid = (int)threadIdx.x;
  const int lane = tid & 63;
  const int w = tid >> 6;
  const int g = lane >> 4;
  const int c = lane & 15;

  __shared__ __align__(16) unsigned char xb0[16384];  // X0 (K=128)
  __shared__ __align__(16) unsigned char xb1[8192];   // X1 / X3
  __shared__ __align__(16) unsigned char xb2[8192];   // X2 = o (bf16)
  __shared__ float bias_s[256];                       // b1|b2|A2_b|A3_w
  __shared__ float lpart[4][64];
  __shared__ float att_s[64];
  __shared__ float h_s[4][128];

  // resident per-wave weight frags: 10 short8 = 40 VGPR
  short8 Wf1[4], Wf2[2], Wf3[2], Wf4[2];
#pragma unroll
  for (int s = 0; s < 4; ++s) Wf1[s] = pf[(w * 4 + s) * 64 + lane];
#pragma unroll
  for (int s = 0; s < 2; ++s) {
    Wf2[s] = pf[1024 + (w * 2 + s) * 64 + lane];
    Wf3[s] = pf[1536 + (w * 2 + s) * 64 + lane];
    Wf4[s] = pf[2048 + (w * 2 + s) * 64 + lane];
  }
  if (tid < 64) {
    bias_s[tid]       = W1_b[tid];
    bias_s[64 + tid]  = W2_b[tid];
    bias_s[128 + tid] = A2_b[tid];
    bias_s[192 + tid] = A3_w[tid];
  }

  const float b3 = A3_b[0];
  const float owb = Ow_b[lane];
  const unsigned short* rbase = ur_bf + NUE;
  const int Wtot = *Wptr;
  const int stride = gridDim.x;

  // staging per-lane constants: batch b covers rows b*4 + (lane>>4),
  // linear chunk ch' = lane&15; source chunk chs = ch' ^ (row&7).
  const int r0 = lane >> 4;                 // 0..3
  const int cE = (lane & 15) ^ r0;          // chunk for b = 0, 2
  const int cO = (lane & 15) ^ (r0 + 4);    // chunk for b = 1, 3
  const unsigned short* tabE = ((cE < 8) ? ur_bf : rbase) + (cE & 7) * 8;
  const unsigned short* tabO = ((cO < 8) ? ur_bf : rbase) + (cO & 7) * 8;
  const int* histE = (cE < 8) ? pu_history : pr_history;
  const int* histO = (cO < 8) ? pu_history : pr_history;
  unsigned char* const sbase = xb0 + w * 4096;

  // ---- prologue: stage window blockIdx.x into xb0 (slot w) ----
  if (blockIdx.x < Wtot) {
    const int dn = wdesc[blockIdx.x * 4 + w];
    if (dn >= 0) {
      const int nd = (dn & 0x3FFF) * LL + (((dn >> 14) & 3) << 4);
      const int lim = ((dn >> 16) & 63) - (((dn >> 14) & 3) << 4);
#pragma unroll
      for (int b = 0; b < 4; ++b) {
        const int row = b * 4 + r0;
        const int* hh = (b & 1) ? histO : histE;
        const unsigned short* tt = (b & 1) ? tabO : tabE;
        if (row < lim) {
          const int idx = hh[nd + row];
          gl_lds16(tt + (size_t)idx * EE, sbase + b * 1024);
        }
      }
    }
  }
  __syncthreads();

  for (int wi = blockIdx.x; wi < Wtot; wi += stride) {
    // current-window descriptors (broadcast loads, L2-hot)
    const int d0 = wdesc[wi * 4 + 0];
    const int d1 = wdesc[wi * 4 + 1];
    const int d2 = wdesc[wi * 4 + 2];
    const int d3 = wdesc[wi * 4 + 3];

    // ---- prefetch NEXT window's staging indices (hides under L1) ----
    const int win = wi + stride;
    int sidx0 = 0, sidx1 = 0, sidx2 = 0, sidx3 = 0;
    int svmask = 0;
    if (win < Wtot) {
      const int dn = wdesc[win * 4 + w];
      if (dn >= 0) {
        const int nd = (dn & 0x3FFF) * LL + (((dn >> 14) & 3) << 4);
        const int lim = ((dn >> 16) & 63) - (((dn >> 14) & 3) << 4);
        if (r0 + 0  < lim) { sidx0 = histE[nd + r0];      svmask |= 1; }
        if (r0 + 4  < lim) { sidx1 = histO[nd + r0 + 4];  svmask |= 2; }
        if (r0 + 8  < lim) { sidx2 = histE[nd + r0 + 8];  svmask |= 4; }
        if (r0 + 12 < lim) { sidx3 = histO[nd + r0 + 12]; svmask |= 8; }
      }
    }

    f32x4 acc[4];

    // ---- L1: X1 = relu(X0 @ W1 + b1), K=128 ----
    {
      const f32x4 binit = ld4(bias_s + 16 * w + 4 * g);
#pragma unroll
      for (int rt = 0; rt < 4; ++rt) acc[rt] = binit;
#pragma unroll
      for (int s = 0; s < 4; ++s)
#pragma unroll
        for (int rt = 0; rt < 4; ++rt) {
          const int row = rt * 16 + c;
          const short8 bf =
              *(const short8*)(xb0 + SWZ(row, row * 256 + s * 64 + g * 16));
          acc[rt] = MFMA(Wf1[s], bf, acc[rt]);
        }
#pragma unroll
      for (int rt = 0; rt < 4; ++rt) {
        const f32x4 v = relu4(acc[rt]);
        ushort4 p;
        p.x = f2bf(v[0]); p.y = f2bf(v[1]); p.z = f2bf(v[2]); p.w = f2bf(v[3]);
        const int row = rt * 16 + c;
        *(ushort4*)(xb1 + SWZ(row, row * 128 + w * 32 + g * 8)) = p;
      }
    }
    __syncthreads();  // B1: xb1 ready; xb0 FREE

    // ---- issue async staging of next window into xb0 (reg-free) ----
    if (svmask & 1) gl_lds16(tabE + (size_t)sidx0 * EE, sbase);
    if (svmask & 2) gl_lds16(tabO + (size_t)sidx1 * EE, sbase + 1024);
    if (svmask & 4) gl_lds16(tabE + (size_t)sidx2 * EE, sbase + 2048);
    if (svmask & 8) gl_lds16(tabO + (size_t)sidx3 * EE, sbase + 3072);

    // ---- L2: o = relu(X1 @ W2 + b2) ----
    {
      const f32x4 binit = ld4(bias_s + 64 + 16 * w + 4 * g);
#pragma unroll
      for (int rt = 0; rt < 4; ++rt) acc[rt] = binit;
#pragma unroll
      for (int s = 0; s < 2; ++s)
#pragma unroll
        for (int rt = 0; rt < 4; ++rt) {
          const int row = rt * 16 + c;
          const short8 bf =
              *(const short8*)(xb1 + SWZ(row, row * 128 + s * 64 + g * 16));
          acc[rt] = MFMA(Wf2[s], bf, acc[rt]);
        }
#pragma unroll
      for (int rt = 0; rt < 4; ++rt) {
        const f32x4 v = relu4(acc[rt]);
        ushort4 p;
        p.x = f2bf(v[0]); p.y = f2bf(v[1]); p.z = f2bf(v[2]); p.w = f2bf(v[3]);
        const int row = rt * 16 + c;
        *(ushort4*)(xb2 + SWZ(row, row * 128 + w * 32 + g * 8)) = p;
      }
    }
    __syncthreads();  // B2: xb2 ready; staging drained here (under L2)

    // ---- L3: a1 = relu(o @ A1[0:64] + abase[node(rt)]) -> xb1 ----
    {
      {
        const int n0 = (d0 >= 0) ? (d0 & 0x3FFF) : 0;
        const int n1 = (d1 >= 0) ? (d1 & 0x3FFF) : 0;
        const int n2 = (d2 >= 0) ? (d2 & 0x3FFF) : 0;
        const int n3 = (d3 >= 0) ? (d3 & 0x3FFF) : 0;
        acc[0] = ld4(abase_ws + (size_t)n0 * EE + 16 * w + 4 * g);
        acc[1] = ld4(abase_ws + (size_t)n1 * EE + 16 * w + 4 * g);
        acc[2] = ld4(abase_ws + (size_t)n2 * EE + 16 * w + 4 * g);
        acc[3] = ld4(abase_ws + (size_t)n3 * EE + 16 * w + 4 * g);
      }
#pragma unroll
      for (int s = 0; s < 2; ++s)
#pragma unroll
        for (int rt = 0; rt < 4; ++rt) {
          const int row = rt * 16 + c;
          const short8 bf =
              *(const short8*)(xb2 + SWZ(row, row * 128 + s * 64 + g * 16));
          acc[rt] = MFMA(Wf3[s], bf, acc[rt]);
        }
#pragma unroll
      for (int rt = 0; rt < 4; ++rt) {
        const f32x4 v = relu4(acc[rt]);
        ushort4 p;
        p.x = f2bf(v[0]); p.y = f2bf(v[1]); p.z = f2bf(v[2]); p.w = f2bf(v[3]);
        const int row = rt * 16 + c;
        *(ushort4*)(xb1 + SWZ(row, row * 128 + w * 32 + g * 8)) = p;
      }
    }
    __syncthreads();  // B3

    // ---- L4: a2 = relu(X3 @ A2 + b); logit partials ----
    {
      const f32x4 binit = ld4(bias_s + 128 + 16 * w + 4 * g);
#pragma unroll
      for (int rt = 0; rt < 4; ++rt) acc[rt] = binit;
#pragma unroll
      for (int s = 0; s < 2; ++s)
#pragma unroll
        for (int rt = 0; rt < 4; ++rt) {
          const int row = rt * 16 + c;
          const short8 bf =
              *(const short8*)(xb1 + SWZ(row, row * 128 + s * 64 + g * 16));
          acc[rt] = MFMA(Wf4[s], bf, acc[rt]);
        }
      const f32x4 a3 = ld4(bias_s + 192 + 16 * w + 4 * g);
#pragma unroll
      for (int rt = 0; rt < 4; ++rt) {
        const f32x4 r = relu4(acc[rt]);
        float p = r[0] * a3[0];
        p = fmaf(r[1], a3[1], p);
        p = fmaf(r[2], a3[2], p);
        p = fmaf(r[3], a3[3], p);
        p += __shfl_xor(p, 16);
        p += __shfl_xor(p, 32);
        if (lane < 16) lpart[w][rt * 16 + lane] = p;
      }
    }
    __syncthreads();  // B4: lpart ready; xb1 free

    // ---- finish: wave w owns node with tile0 at slot w ----
    {
      const int dw = (w == 0) ? d0 : (w == 1) ? d1 : (w == 2) ? d2 : d3;
      if (dw >= 0 && ((dw >> 14) & 3) == 0) {
        const int fnode = dw & 0x3FFF;
        const int flen = (dw >> 16) & 63;
        const bool vr = (lane < flen);
        float lg = -INFINITY;
        if (vr) {
          const int row = w * 16 + lane;
          lg = lpart[0][row] + lpart[1][row] + lpart[2][row] + lpart[3][row] + b3;
        }
        float mx = lg;
#pragma unroll
        for (int off = 32; off > 0; off >>= 1)
          mx = fmaxf(mx, __shfl_xor(mx, off));
        const float e = __expf(lg - mx);
        float sm = e;
#pragma unroll
        for (int off = 32; off > 0; off >>= 1) sm += __shfl_xor(sm, off);
        if (vr) att_s[w * 16 + lane] = e / sm;

        float h0 = 0.f, h1 = 0.f;
        for (int r2 = 0; r2 + 1 < flen; r2 += 2) {
          const int ra = w * 16 + r2, rb = ra + 1;
          const unsigned short oa =
              *(const unsigned short*)(xb2 + SWZ(ra, ra * 128 + lane * 2));
          const unsigned short ob =
              *(const unsigned short*)(xb2 + SWZ(rb, rb * 128 + lane * 2));
          h0 = fmaf(att_s[ra], bf2f(oa), h0);
          h1 = fmaf(att_s[rb], bf2f(ob), h1);
        }
        if (flen & 1) {
          const int ra = w * 16 + flen - 1;
          const unsigned short oa =
              *(const unsigned short*)(xb2 + SWZ(ra, ra * 128 + lane * 2));
          h0 = fmaf(att_s[ra], bf2f(oa), h0);
        }
        h_s[w][lane] = h0 + h1;
        h_s[w][64 + lane] = post_ws[(size_t)fnode * EE + lane];

        float s0 = 0.f, s1 = 0.f, s2 = 0.f, s3 = 0.f;
#pragma unroll 8
        for (int k = 0; k < 128; k += 4) {
          s0 = fmaf(h_s[w][k],     Ow_w[(k)     * EE + lane], s0);
          s1 = fmaf(h_s[w][k + 1], Ow_w[(k + 1) * EE + lane], s1);
          s2 = fmaf(h_s[w][k + 2], Ow_w[(k + 2) * EE + lane], s2);
          s3 = fmaf(h_s[w][k + 3], Ow_w[(k + 3) * EE + lane], s3);
        }
        const float a = owb + ((s0 + s1) + (s2 + s3));
        out[(size_t)fnode * EE + lane] = fmaxf(a, 0.f);
      }
    }
    // NO barrier here: next window's first xb2/lpart/att_s writes are >=1
    // full barrier away (L2 after B1; L4 after B3); xb0 staging drained at B2.
  }
}

// ---------------- R1 fallback (all-f32, no workspace) ----------------
template <int K>
__device__ __forceinline__ void mm2(const float* row0, const float* row1,
                                    const float* __restrict__ W, int e,
                                    float& acc0, float& acc1) {
  const float4* r0 = (const float4*)row0;
  const float4* r1 = (const float4*)row1;
#pragma unroll 4
  for (int k4 = 0; k4 < K / 4; ++k4) {
    float4 va = r0[k4];
    float4 vb = r1[k4];
    const float* w = W + (k4 * 4) * EE + e;
    float w0 = w[0], w1 = w[EE], w2 = w[2 * EE], w3 = w[3 * EE];
    acc0 = fmaf(va.x, w0, acc0);  acc1 = fmaf(vb.x, w0, acc1);
    acc0 = fmaf(va.y, w1, acc0);  acc1 = fmaf(vb.y, w1, acc1);
    acc0 = fmaf(va.z, w2, acc0);  acc1 = fmaf(vb.z, w2, acc1);
    acc0 = fmaf(va.w, w3, acc0);  acc1 = fmaf(vb.w, w3, acc1);
  }
}

__global__ __launch_bounds__(256, 4)
void postenc_kernel(
    const float* __restrict__ u2e, const float* __restrict__ r2e,
    const float* __restrict__ content_emb,
    const float* __restrict__ We_w, const float* __restrict__ We_b,
    const float* __restrict__ W1_w, const float* __restrict__ W1_b,
    const float* __restrict__ W2_w, const float* __restrict__ W2_b,
    const float* __restrict__ A1_w, const float* __restrict__ A1_b,
    const float* __restrict__ A2_w, const float* __restrict__ A2_b,
    const float* __restrict__ A3_w, const float* __restrict__ A3_b,
    const float* __restrict__ Ow_w, const float* __restrict__ Ow_b,
    const int* __restrict__ pu_history, const int* __restrict__ pr_history,
    const int* __restrict__ lengths, const int* __restrict__ pr_content,
    float* __restrict__ out) {
  const int n = blockIdx.x;
  const int tid = (int)threadIdx.x;
  const int e = tid & 63;
  const int g = tid >> 6;

  __shared__ float post_s[EE];
  __shared__ float abase_s[EE];
  __shared__ float in_s[8][128];
  __shared__ float x_s[8][EE];
  __shared__ float a_s[8][EE];
  __shared__ float o_s[56][EE];
  __shared__ float logit_s[EE];
  __shared__ float att_s[EE];
  __shared__ float red_s[4][EE];

  const int len = lengths[n];
  float p = 0.f;

  if (g == 0) {
    const float* ce = content_emb + (size_t)pr_content[n] * 128;
    float acc = We_b[e];
#pragma unroll 4
    for (int k = 0; k < 128; ++k) acc = fmaf(ce[k], We_w[k * EE + e], acc);
    p = fmaxf(acc, 0.f);
    post_s[e] = p;
    float ab = A1_b[e];
#pragma unroll
    for (int k = 0; k < 64; ++k) {
      float pk = __shfl(p, k);
      ab = fmaf(pk, A1_w[(64 + k) * EE + e], ab);
    }
    abase_s[e] = ab;
    logit_s[e] = -INFINITY;
  }
  __syncthreads();

  for (int lb = 0; lb < 56; lb += 8) {
    const int l0 = lb + g;
    const int l1 = l0 + 4;
    const bool v0 = l0 < LL;
    const bool v1 = l1 < LL;

    int pu0 = 0, pr0 = 0, pu1 = 0, pr1 = 0;
    if (v0) { pu0 = pu_history[n * LL + l0]; pr0 = pr_history[n * LL + l0]; }
    if (v1) { pu1 = pu_history[n * LL + l1]; pr1 = pr_history[n * LL + l1]; }
    in_s[g][e]          = v0 ? u2e[(size_t)pu0 * EE + e] : 0.f;
    in_s[g][64 + e]     = v0 ? r2e[pr0 * EE + e]         : 0.f;
    in_s[g + 4][e]      = v1 ? u2e[(size_t)pu1 * EE + e] : 0.f;
    in_s[g + 4][64 + e] = v1 ? r2e[pr1 * EE + e]         : 0.f;
    __syncthreads();

    float acc0 = W1_b[e], acc1 = acc0;
    mm2<128>(in_s[g], in_s[g + 4], W1_w, e, acc0, acc1);
    x_s[g][e]     = fmaxf(acc0, 0.f);
    x_s[g + 4][e] = fmaxf(acc1, 0.f);
    __syncthreads();

    acc0 = W2_b[e]; acc1 = acc0;
    mm2<64>(x_s[g], x_s[g + 4], W2_w, e, acc0, acc1);
    float o0 = fmaxf(acc0, 0.f);
    float o1 = fmaxf(acc1, 0.f);
    if (v0) o_s[l0][e] = o0;
    if (v1) o_s[l1][e] = o1;
    x_s[g][e]     = o0;
    x_s[g + 4][e] = o1;
    __syncthreads();

    acc0 = abase_s[e]; acc1 = acc0;
    mm2<64>(x_s[g], x_s[g + 4], A1_w, e, acc0, acc1);
    a_s[g][e]     = fmaxf(acc0, 0.f);
    a_s[g + 4][e] = fmaxf(acc1, 0.f);
    __syncthreads();

    acc0 = A2_b[e]; acc1 = acc0;
    mm2<64>(a_s[g], a_s[g + 4], A2_w, e, acc0, acc1);
    float w3 = A3_w[e];
    float p0 = fmaxf(acc0, 0.f) * w3;
    float p1 = fmaxf(acc1, 0.f) * w3;
#pragma unroll
    for (int off = 32; off > 0; off >>= 1) {
      p0 += __shfl_xor(p0, off);
      p1 += __shfl_xor(p1, off);
    }
    if (e == 0) {
      float b3 = A3_b[0];
      if (l0 < len) logit_s[l0] = p0 + b3;
      if (l1 < len) logit_s[l1] = p1 + b3;
    }
    __syncthreads();
  }

  if (g == 0) {
    float lg = logit_s[e];
    float m = lg;
#pragma unroll
    for (int off = 32; off > 0; off >>= 1) m = fmaxf(m, __shfl_xor(m, off));
    float pe = __expf(lg - m);
    float sm = pe;
#pragma unroll
    for (int off = 32; off > 0; off >>= 1) sm += __shfl_xor(sm, off);
    att_s[e] = pe / sm;
  }
  __syncthreads();

  {
    const int l_lo = 13 * g;
    const int l_hi = (13 * g + 13 < LL) ? 13 * g + 13 : LL;
    float h = 0.f;
    for (int l = l_lo; l < l_hi; ++l) h = fmaf(att_s[l], o_s[l][e], h);
    red_s[g][e] = h;
  }
  __syncthreads();

  if (g == 0) {
    float h = red_s[0][e] + red_s[1][e] + red_s[2][e] + red_s[3][e];
    float acc = Ow_b[e];
#pragma unroll
    for (int k = 0; k < 64; ++k) {
      float hk = __shfl(h, k);
      acc = fmaf(hk, Ow_w[k * EE + e], acc);
    }
#pragma unroll
    for (int k = 0; k < 64; ++k) {
      float pk = __shfl(p, k);
      acc = fmaf(pk, Ow_w[(64 + k) * EE + e], acc);
    }
    out[(size_t)n * EE + e] = fmaxf(acc, 0.f);
  }
}

// ---------------- launcher ----------------
extern "C" void kernel_launch(void* const* d_in, const int* in_sizes, int n_in,
                              void* d_out, int out_size, void* d_ws, size_t ws_size,
                              hipStream_t stream) {
  const float* u2e         = (const float*)d_in[0];
  const float* r2e         = (const float*)d_in[1];
  const float* content_emb = (const float*)d_in[2];
  const float* We_w = (const float*)d_in[3];
  const float* We_b = (const float*)d_in[4];
  const float* W1_w = (const float*)d_in[5];
  const float* W1_b = (const float*)d_in[6];
  const float* W2_w = (const float*)d_in[7];
  const float* W2_b = (const float*)d_in[8];
  const float* A1_w = (const float*)d_in[9];
  const float* A1_b = (const float*)d_in[10];
  const float* A2_w = (const float*)d_in[11];
  const float* A2_b = (const float*)d_in[12];
  const float* A3_w = (const float*)d_in[13];
  const float* A3_b = (const float*)d_in[14];
  const float* Ow_w = (const float*)d_in[15];
  const float* Ow_b = (const float*)d_in[16];
  // d_in[17] = nodes (unused)
  const int* pu_history = (const int*)d_in[18];
  const int* pr_history = (const int*)d_in[19];
  const int* lengths    = (const int*)d_in[20];
  const int* pr_content = (const int*)d_in[21];
  float* out = (float*)d_out;

  // workspace layout (bytes)
  const size_t FR_OFF  = 0;                               // frags 40960B
  const size_t PO_OFF  = 65536;
  const size_t AB_OFF  = PO_OFF + (size_t)NN * EE * 4;    // +4MB
  const size_t UBF_OFF = AB_OFF + (size_t)NN * EE * 4;    // +4MB
  const size_t CNT_OFF = UBF_OFF + (size_t)(NUE + 384) * 2;
  const size_t BK_OFF  = CNT_OFF + 256;
  const size_t WD_OFF  = BK_OFF + (size_t)4 * NN * 4;
  const size_t NEED    = WD_OFF + (size_t)NN * 4 * 4;     // ~20.8 MB

  if (ws_size < NEED) {
    postenc_kernel<<<NN, 256, 0, stream>>>(
        u2e, r2e, content_emb, We_w, We_b, W1_w, W1_b, W2_w, W2_b,
        A1_w, A1_b, A2_w, A2_b, A3_w, A3_b, Ow_w, Ow_b,
        pu_history, pr_history, lengths, pr_content, out);
    return;
  }

  char* wsp = (char*)d_ws;
  unsigned short* frag_ws = (unsigned short*)(wsp + FR_OFF);
  float* post_ws  = (float*)(wsp + PO_OFF);
  float* abase_ws = (float*)(wsp + AB_OFF);
  unsigned short* ur_bf = (unsigned short*)(wsp + UBF_OFF);
  int* Wout_ws = (int*)(wsp + CNT_OFF);
  int* bk_ws   = (int*)(wsp + BK_OFF);
  int* wd_ws   = (int*)(wsp + WD_OFF);

  pre_kernel<<<1540, 1024, 0, stream>>>(
      u2e, r2e, content_emb, pr_content, We_w, We_b, W1_w, W2_w,
      A1_w, A1_b, A2_w, lengths, ur_bf, bk_ws, wd_ws, Wout_ws,
      frag_ws, post_ws, abase_ws);
  fused_kernel<<<1024, 256, 0, stream>>>(
      ur_bf, W1_b, W2_b, A2_b, A3_w, A3_b, Ow_w, Ow_b,
      pu_history, pr_history, (const short8*)frag_ws,
      post_ws, abase_ws, wd_ws, Wout_ws, out);
}

// Round 16
// 131.247 us; speedup vs baseline: 1.6325x; 1.0446x over previous
//
#include <hip/hip_runtime.h>
#include <hip/hip_bf16.h>
#include <math.h>

// PostEncode R16: R15 + lgkm-only raw barriers (T3/T4 counted-wait pattern).
// R15 post-mortem: fused latency-chain-bound; __syncthreads at B2 force-
// drains (vmcnt(0)) the async gl_lds16 staging with only ~300cy of cover.
// R16: B1/B2/B3 = raw {s_waitcnt lgkmcnt(0); s_barrier} (LDS-only hazards,
// audited); B4 stays __syncthreads -> staging drains there with ~3 phases
// (~1200cy) of cover. post_ws load hoisted to loop top (+1 VGPR).

#define NN 16384
#define LL 50
#define EE 64
#define NUE 6400000  // u2e bf16 elements; r2e table follows

typedef __attribute__((ext_vector_type(8))) short short8;
typedef __attribute__((ext_vector_type(4))) float f32x4;

// LDS-only barrier: wait own LDS ops, sync; leaves vmcnt outstanding.
#define LGKM_BAR() asm volatile("s_waitcnt lgkmcnt(0)\n\ts_barrier" ::: "memory")

static __device__ __forceinline__ unsigned short f2bf(float x) {
  __hip_bfloat16 h = __float2bfloat16(x);
  unsigned short u;
  __builtin_memcpy(&u, &h, 2);
  return u;
}

static __device__ __forceinline__ float bf2f(unsigned short u) {
  unsigned int v = ((unsigned int)u) << 16;
  float f;
  __builtin_memcpy(&f, &v, 4);
  return f;
}

static __device__ __forceinline__ f32x4 ld4(const float* p) {
  return *(const f32x4*)p;
}

static __device__ __forceinline__ f32x4 relu4(f32x4 a) {
  f32x4 r;
  r[0] = fmaxf(a[0], 0.f); r[1] = fmaxf(a[1], 0.f);
  r[2] = fmaxf(a[2], 0.f); r[3] = fmaxf(a[3], 0.f);
  return r;
}

// async 16B/lane global->LDS; lds dest = wave-uniform base + lane*16
static __device__ __forceinline__ void gl_lds16(const unsigned short* g,
                                                unsigned char* l) {
  __builtin_amdgcn_global_load_lds(
      (const __attribute__((address_space(1))) void*)g,
      (__attribute__((address_space(3))) void*)l, 16, 0, 0);
}

#define MFMA(A, B, C) __builtin_amdgcn_mfma_f32_16x16x32_bf16((A), (B), (C), 0, 0, 0)
#define SWZ(row, byteoff) ((byteoff) ^ (((row) & 7) << 4))

// ---------------- mega-pre (1024-thr blocks, grid 1540) ----------------
// block 0: bucket+wdesc ; [1,513): conv ; [513,1537): setup ; [1537,1540): pack
__global__ __launch_bounds__(1024)
void pre_kernel(const float* __restrict__ u2e, const float* __restrict__ r2e,
                const float* __restrict__ content_emb,
                const int* __restrict__ pr_content,
                const float* __restrict__ We_w, const float* __restrict__ We_b,
                const float* __restrict__ W1_w, const float* __restrict__ W2_w,
                const float* __restrict__ A1_w, const float* __restrict__ A1_b,
                const float* __restrict__ A2_w,
                const int* __restrict__ lengths,
                unsigned short* __restrict__ ur_bf,
                int* __restrict__ buckets, int* __restrict__ wdesc,
                int* __restrict__ Wout, unsigned short* __restrict__ frag_ws,
                float* __restrict__ post_ws, float* __restrict__ abase_ws) {
  const int b = blockIdx.x;
  const int tid = (int)threadIdx.x;
  __shared__ float ce_s[16][128];
  __shared__ float post_s[16][64];
  __shared__ int cnt_s[4];

  if (b == 0) {
    // ---- bucket (ballot-aggregated, 16 waves) + wdesc ----
    const int lanei = tid & 63;
    if (tid < 4) cnt_s[tid] = 0;
    __syncthreads();
    for (int i0 = 0; i0 < NN; i0 += 1024) {
      const int n = i0 + tid;
      const int ln = lengths[n];
      const int nt = (ln + 15) >> 4;  // 1..4
      const int entry = n | (ln << 14);
#pragma unroll
      for (int bb = 1; bb <= 4; ++bb) {
        const unsigned long long mask = __ballot(nt == bb);
        if (mask) {
          const int leader = __ffsll((long long)mask) - 1;
          int base = 0;
          if (lanei == leader)
            base = atomicAdd(&cnt_s[bb - 1], (int)__popcll(mask));
          base = __shfl(base, leader);
          if (nt == bb) {
            const int rank = __popcll(mask & ((1ull << lanei) - 1ull));
            buckets[(bb - 1) * NN + base + rank] = entry;
          }
        }
      }
    }
    __syncthreads();

    const int c1 = cnt_s[0], c2 = cnt_s[1], c3 = cnt_s[2], c4 = cnt_s[3];
    const int u1 = (c1 < c3) ? c1 : c3;
    const int p2 = c2 >> 1, odd2 = c2 & 1;
    const int rem1 = c1 - u1;
    const int o2ones = odd2 ? ((rem1 < 2) ? rem1 : 2) : 0;
    const int rem1b = rem1 - o2ones;
    const int w4 = c4, w3 = c3, w2 = p2 + odd2, w1 = (rem1b + 3) >> 2;
    const int W = w4 + w3 + w2 + w1;
    if (tid == 0) *Wout = W;

    const int* b1 = buckets;
    const int* b2 = buckets + NN;
    const int* b3 = buckets + 2 * NN;
    const int* b4 = buckets + 3 * NN;
    // entry e = n | len<<14 ; dsc = node | tile<<14 | len<<16 (pure ALU)
#define ENC(e, t) (((e) & 0x3FFF) | ((t) << 14) | (((e) >> 14) << 16))
    for (int w = tid; w < W; w += 1024) {
      int d0 = -1, d1 = -1, d2 = -1, d3 = -1;
      if (w < w4) {
        const int e = b4[w];
        d0 = ENC(e, 0); d1 = ENC(e, 1); d2 = ENC(e, 2); d3 = ENC(e, 3);
      } else if (w < w4 + w3) {
        const int i = w - w4;
        const int e = b3[i];
        d0 = ENC(e, 0); d1 = ENC(e, 1); d2 = ENC(e, 2);
        if (i < u1) d3 = ENC(b1[i], 0);
      } else if (w < w4 + w3 + w2) {
        const int i = w - w4 - w3;
        if (i < p2) {
          const int ea = b2[2 * i], eb = b2[2 * i + 1];
          d0 = ENC(ea, 0); d1 = ENC(ea, 1); d2 = ENC(eb, 0); d3 = ENC(eb, 1);
        } else {
          const int ea = b2[c2 - 1];
          d0 = ENC(ea, 0); d1 = ENC(ea, 1);
          if (o2ones > 0) d2 = ENC(b1[u1], 0);
          if (o2ones > 1) d3 = ENC(b1[u1 + 1], 0);
        }
      } else {
        const int i = w - w4 - w3 - w2;
        const int basei = u1 + o2ones + 4 * i;
        if (basei + 0 < c1) d0 = ENC(b1[basei + 0], 0);
        if (basei + 1 < c1) d1 = ENC(b1[basei + 1], 0);
        if (basei + 2 < c1) d2 = ENC(b1[basei + 2], 0);
        if (basei + 3 < c1) d3 = ENC(b1[basei + 3], 0);
      }
      int4 v; v.x = d0; v.y = d1; v.z = d2; v.w = d3;
      *(int4*)(wdesc + 4 * w) = v;
    }
#undef ENC
  } else if (b < 513) {
    // ---- conv: u2e,r2e f32 -> bf16 tables ----
    const int total8 = (NUE + 384) / 8;
    for (int i = (b - 1) * 1024 + tid; i < total8; i += 512 * 1024) {
      const long long e0 = (long long)i * 8;
      const float* src = (e0 < NUE) ? (u2e + e0) : (r2e + (e0 - NUE));
      float4 a = *(const float4*)src;
      float4 bb = *(const float4*)(src + 4);
      short8 v;
      v[0] = (short)f2bf(a.x); v[1] = (short)f2bf(a.y);
      v[2] = (short)f2bf(a.z); v[3] = (short)f2bf(a.w);
      v[4] = (short)f2bf(bb.x); v[5] = (short)f2bf(bb.y);
      v[6] = (short)f2bf(bb.z); v[7] = (short)f2bf(bb.w);
      *reinterpret_cast<short8*>(ur_bf + e0) = v;
    }
  } else if (b < 1537) {
    // ---- setup: post + abase, 16 nodes/block ----
    const int sub = tid >> 6;
    const int e = tid & 63;
    const int n = (b - 513) * 16 + sub;
    const float* ce = content_emb + (size_t)pr_content[n] * 128;
    ce_s[sub][e] = ce[e];
    ce_s[sub][64 + e] = ce[64 + e];
    __syncthreads();
    float acc = We_b[e];
#pragma unroll 8
    for (int k = 0; k < 128; ++k)
      acc = fmaf(ce_s[sub][k], We_w[k * EE + e], acc);
    float po = fmaxf(acc, 0.f);
    post_s[sub][e] = po;
    post_ws[(size_t)n * EE + e] = po;
    __syncthreads();
    float ab = A1_b[e];
#pragma unroll 8
    for (int k = 0; k < 64; ++k)
      ab = fmaf(post_s[sub][k], A1_w[(64 + k) * EE + e], ab);
    abase_ws[(size_t)n * EE + e] = ab;
  } else {
    // ---- pack: weights -> frag-ordered bf16, one frag per thread ----
    const int idx = (b - 1537) * 1024 + tid;
    if (idx < 2560) {
      const float* Wm;
      int w, s, lane;
      if (idx < 1024) {
        w = idx >> 8; s = (idx >> 6) & 3; lane = idx & 63; Wm = W1_w;
      } else {
        int r = idx - 1024;
        int li = r >> 9;
        w = (r >> 7) & 3; s = (r >> 6) & 1; lane = r & 63;
        Wm = (li == 0) ? W2_w : (li == 1) ? A1_w : A2_w;
      }
      const int g = lane >> 4, c = lane & 15;
#pragma unroll
      for (int j = 0; j < 8; ++j)
        frag_ws[idx * 8 + j] = f2bf(Wm[(32 * s + 8 * g + j) * EE + 16 * w + c]);
    }
  }
}

// ---------------- fused: window GEMM, raw lgkm barriers ----------------
__global__
__attribute__((amdgpu_flat_work_group_size(256, 256)))
__attribute__((amdgpu_waves_per_eu(4, 4)))
void fused_kernel(const unsigned short* __restrict__ ur_bf,
                  const float* __restrict__ W1_b, const float* __restrict__ W2_b,
                  const float* __restrict__ A2_b,
                  const float* __restrict__ A3_w, const float* __restrict__ A3_b,
                  const float* __restrict__ Ow_w, const float* __restrict__ Ow_b,
                  const int* __restrict__ pu_history,
                  const int* __restrict__ pr_history,
                  const short8* __restrict__ pf,
                  const float* __restrict__ post_ws,
                  const float* __restrict__ abase_ws,
                  const int* __restrict__ wdesc, const int* __restrict__ Wptr,
                  float* __restrict__ out) {
  const int tid = (int)threadIdx.x;
  const int lane = tid & 63;
  const int w = tid >> 6;
  const int g = lane >> 4;
  const int c = lane & 15;

  __shared__ __align__(16) unsigned char xb0[16384];  // X0 (K=128)
  __shared__ __align__(16) unsigned char xb1[8192];   // X1 / X3
  __shared__ __align__(16) unsigned char xb2[8192];   // X2 = o (bf16)
  __shared__ float bias_s[256];                       // b1|b2|A2_b|A3_w
  __shared__ float lpart[4][64];
  __shared__ float att_s[64];
  __shared__ float h_s[4][128];

  // resident per-wave weight frags: 10 short8 = 40 VGPR
  short8 Wf1[4], Wf2[2], Wf3[2], Wf4[2];
#pragma unroll
  for (int s = 0; s < 4; ++s) Wf1[s] = pf[(w * 4 + s) * 64 + lane];
#pragma unroll
  for (int s = 0; s < 2; ++s) {
    Wf2[s] = pf[1024 + (w * 2 + s) * 64 + lane];
    Wf3[s] = pf[1536 + (w * 2 + s) * 64 + lane];
    Wf4[s] = pf[2048 + (w * 2 + s) * 64 + lane];
  }
  if (tid < 64) {
    bias_s[tid]       = W1_b[tid];
    bias_s[64 + tid]  = W2_b[tid];
    bias_s[128 + tid] = A2_b[tid];
    bias_s[192 + tid] = A3_w[tid];
  }

  const float b3 = A3_b[0];
  const float owb = Ow_b[lane];
  const unsigned short* rbase = ur_bf + NUE;
  const int Wtot = *Wptr;
  const int stride = gridDim.x;

  // staging per-lane constants: batch b covers rows b*4 + (lane>>4),
  // linear chunk ch' = lane&15; source chunk chs = ch' ^ (row&7).
  const int r0 = lane >> 4;                 // 0..3
  const int cE = (lane & 15) ^ r0;          // chunk for b = 0, 2
  const int cO = (lane & 15) ^ (r0 + 4);    // chunk for b = 1, 3
  const unsigned short* tabE = ((cE < 8) ? ur_bf : rbase) + (cE & 7) * 8;
  const unsigned short* tabO = ((cO < 8) ? ur_bf : rbase) + (cO & 7) * 8;
  const int* histE = (cE < 8) ? pu_history : pr_history;
  const int* histO = (cO < 8) ? pu_history : pr_history;
  unsigned char* const sbase = xb0 + w * 4096;

  // ---- prologue: stage window blockIdx.x into xb0 (slot w) ----
  if (blockIdx.x < Wtot) {
    const int dn = wdesc[blockIdx.x * 4 + w];
    if (dn >= 0) {
      const int nd = (dn & 0x3FFF) * LL + (((dn >> 14) & 3) << 4);
      const int lim = ((dn >> 16) & 63) - (((dn >> 14) & 3) << 4);
#pragma unroll
      for (int b = 0; b < 4; ++b) {
        const int row = b * 4 + r0;
        const int* hh = (b & 1) ? histO : histE;
        const unsigned short* tt = (b & 1) ? tabO : tabE;
        if (row < lim) {
          const int idx = hh[nd + row];
          gl_lds16(tt + (size_t)idx * EE, sbase + b * 1024);
        }
      }
    }
  }
  __syncthreads();

  for (int wi = blockIdx.x; wi < Wtot; wi += stride) {
    // current-window descriptors (broadcast loads, L2-hot)
    const int d0 = wdesc[wi * 4 + 0];
    const int d1 = wdesc[wi * 4 + 1];
    const int d2 = wdesc[wi * 4 + 2];
    const int d3 = wdesc[wi * 4 + 3];
    const int dw = (w == 0) ? d0 : (w == 1) ? d1 : (w == 2) ? d2 : d3;
    const bool fin = (dw >= 0) && (((dw >> 14) & 3) == 0);
    const int fnode = dw & 0x3FFF;
    const int flen = (dw >> 16) & 63;

    // ---- prefetch post for finish (1 VGPR, ~4 phases of cover) ----
    float po = 0.f;
    if (fin) po = post_ws[(size_t)fnode * EE + lane];

    // ---- prefetch NEXT window's staging indices (hides under L1) ----
    const int win = wi + stride;
    int sidx0 = 0, sidx1 = 0, sidx2 = 0, sidx3 = 0;
    int svmask = 0;
    if (win < Wtot) {
      const int dn = wdesc[win * 4 + w];
      if (dn >= 0) {
        const int nd = (dn & 0x3FFF) * LL + (((dn >> 14) & 3) << 4);
        const int lim = ((dn >> 16) & 63) - (((dn >> 14) & 3) << 4);
        if (r0 + 0  < lim) { sidx0 = histE[nd + r0];      svmask |= 1; }
        if (r0 + 4  < lim) { sidx1 = histO[nd + r0 + 4];  svmask |= 2; }
        if (r0 + 8  < lim) { sidx2 = histE[nd + r0 + 8];  svmask |= 4; }
        if (r0 + 12 < lim) { sidx3 = histO[nd + r0 + 12]; svmask |= 8; }
      }
    }

    f32x4 acc[4];

    // ---- L1: X1 = relu(X0 @ W1 + b1), K=128 ----
    {
      const f32x4 binit = ld4(bias_s + 16 * w + 4 * g);
#pragma unroll
      for (int rt = 0; rt < 4; ++rt) acc[rt] = binit;
#pragma unroll
      for (int s = 0; s < 4; ++s)
#pragma unroll
        for (int rt = 0; rt < 4; ++rt) {
          const int row = rt * 16 + c;
          const short8 bf =
              *(const short8*)(xb0 + SWZ(row, row * 256 + s * 64 + g * 16));
          acc[rt] = MFMA(Wf1[s], bf, acc[rt]);
        }
#pragma unroll
      for (int rt = 0; rt < 4; ++rt) {
        const f32x4 v = relu4(acc[rt]);
        ushort4 p;
        p.x = f2bf(v[0]); p.y = f2bf(v[1]); p.z = f2bf(v[2]); p.w = f2bf(v[3]);
        const int row = rt * 16 + c;
        *(ushort4*)(xb1 + SWZ(row, row * 128 + w * 32 + g * 8)) = p;
      }
    }
    LGKM_BAR();  // B1 (LDS-only): xb1 ready; xb0 FREE

    // ---- issue async staging of next window into xb0 (reg-free);
    //      drains at B4's vmcnt(0) -> ~3 phases of cover ----
    if (svmask & 1) gl_lds16(tabE + (size_t)sidx0 * EE, sbase);
    if (svmask & 2) gl_lds16(tabO + (size_t)sidx1 * EE, sbase + 1024);
    if (svmask & 4) gl_lds16(tabE + (size_t)sidx2 * EE, sbase + 2048);
    if (svmask & 8) gl_lds16(tabO + (size_t)sidx3 * EE, sbase + 3072);

    // ---- L2: o = relu(X1 @ W2 + b2) ----
    {
      const f32x4 binit = ld4(bias_s + 64 + 16 * w + 4 * g);
#pragma unroll
      for (int rt = 0; rt < 4; ++rt) acc[rt] = binit;
#pragma unroll
      for (int s = 0; s < 2; ++s)
#pragma unroll
        for (int rt = 0; rt < 4; ++rt) {
          const int row = rt * 16 + c;
          const short8 bf =
              *(const short8*)(xb1 + SWZ(row, row * 128 + s * 64 + g * 16));
          acc[rt] = MFMA(Wf2[s], bf, acc[rt]);
        }
#pragma unroll
      for (int rt = 0; rt < 4; ++rt) {
        const f32x4 v = relu4(acc[rt]);
        ushort4 p;
        p.x = f2bf(v[0]); p.y = f2bf(v[1]); p.z = f2bf(v[2]); p.w = f2bf(v[3]);
        const int row = rt * 16 + c;
        *(ushort4*)(xb2 + SWZ(row, row * 128 + w * 32 + g * 8)) = p;
      }
    }
    LGKM_BAR();  // B2 (LDS-only): xb2 ready; staging still in flight

    // ---- L3: a1 = relu(o @ A1[0:64] + abase[node(rt)]) -> xb1 ----
    {
      {
        const int n0 = (d0 >= 0) ? (d0 & 0x3FFF) : 0;
        const int n1 = (d1 >= 0) ? (d1 & 0x3FFF) : 0;
        const int n2 = (d2 >= 0) ? (d2 & 0x3FFF) : 0;
        const int n3 = (d3 >= 0) ? (d3 & 0x3FFF) : 0;
        acc[0] = ld4(abase_ws + (size_t)n0 * EE + 16 * w + 4 * g);
        acc[1] = ld4(abase_ws + (size_t)n1 * EE + 16 * w + 4 * g);
        acc[2] = ld4(abase_ws + (size_t)n2 * EE + 16 * w + 4 * g);
        acc[3] = ld4(abase_ws + (size_t)n3 * EE + 16 * w + 4 * g);
      }
#pragma unroll
      for (int s = 0; s < 2; ++s)
#pragma unroll
        for (int rt = 0; rt < 4; ++rt) {
          const int row = rt * 16 + c;
          const short8 bf =
              *(const short8*)(xb2 + SWZ(row, row * 128 + s * 64 + g * 16));
          acc[rt] = MFMA(Wf3[s], bf, acc[rt]);
        }
#pragma unroll
      for (int rt = 0; rt < 4; ++rt) {
        const f32x4 v = relu4(acc[rt]);
        ushort4 p;
        p.x = f2bf(v[0]); p.y = f2bf(v[1]); p.z = f2bf(v[2]); p.w = f2bf(v[3]);
        const int row = rt * 16 + c;
        *(ushort4*)(xb1 + SWZ(row, row * 128 + w * 32 + g * 8)) = p;
      }
    }
    LGKM_BAR();  // B3 (LDS-only)

    // ---- L4: a2 = relu(X3 @ A2 + b); logit partials ----
    {
      const f32x4 binit = ld4(bias_s + 128 + 16 * w + 4 * g);
#pragma unroll
      for (int rt = 0; rt < 4; ++rt) acc[rt] = binit;
#pragma unroll
      for (int s = 0; s < 2; ++s)
#pragma unroll
        for (int rt = 0; rt < 4; ++rt) {
          const int row = rt * 16 + c;
          const short8 bf =
              *(const short8*)(xb1 + SWZ(row, row * 128 + s * 64 + g * 16));
          acc[rt] = MFMA(Wf4[s], bf, acc[rt]);
        }
      const f32x4 a3 = ld4(bias_s + 192 + 16 * w + 4 * g);
#pragma unroll
      for (int rt = 0; rt < 4; ++rt) {
        const f32x4 r = relu4(acc[rt]);
        float p = r[0] * a3[0];
        p = fmaf(r[1], a3[1], p);
        p = fmaf(r[2], a3[2], p);
        p = fmaf(r[3], a3[3], p);
        p += __shfl_xor(p, 16);
        p += __shfl_xor(p, 32);
        if (lane < 16) lpart[w][rt * 16 + lane] = p;
      }
    }
    __syncthreads();  // B4 (FULL): lpart ready; staging vmcnt drained here

    // ---- finish: wave w owns node with tile0 at slot w ----
    if (fin) {
      const bool vr = (lane < flen);
      float lg = -INFINITY;
      if (vr) {
        const int row = w * 16 + lane;
        lg = lpart[0][row] + lpart[1][row] + lpart[2][row] + lpart[3][row] + b3;
      }
      float mx = lg;
#pragma unroll
      for (int off = 32; off > 0; off >>= 1)
        mx = fmaxf(mx, __shfl_xor(mx, off));
      const float e = __expf(lg - mx);
      float sm = e;
#pragma unroll
      for (int off = 32; off > 0; off >>= 1) sm += __shfl_xor(sm, off);
      if (vr) att_s[w * 16 + lane] = e / sm;

      float h0 = 0.f, h1 = 0.f;
      for (int r2 = 0; r2 + 1 < flen; r2 += 2) {
        const int ra = w * 16 + r2, rb = ra + 1;
        const unsigned short oa =
            *(const unsigned short*)(xb2 + SWZ(ra, ra * 128 + lane * 2));
        const unsigned short ob =
            *(const unsigned short*)(xb2 + SWZ(rb, rb * 128 + lane * 2));
        h0 = fmaf(att_s[ra], bf2f(oa), h0);
        h1 = fmaf(att_s[rb], bf2f(ob), h1);
      }
      if (flen & 1) {
        const int ra = w * 16 + flen - 1;
        const unsigned short oa =
            *(const unsigned short*)(xb2 + SWZ(ra, ra * 128 + lane * 2));
        h0 = fmaf(att_s[ra], bf2f(oa), h0);
      }
      h_s[w][lane] = h0 + h1;
      h_s[w][64 + lane] = po;

      float s0 = 0.f, s1 = 0.f, s2 = 0.f, s3 = 0.f;
#pragma unroll 8
      for (int k = 0; k < 128; k += 4) {
        s0 = fmaf(h_s[w][k],     Ow_w[(k)     * EE + lane], s0);
        s1 = fmaf(h_s[w][k + 1], Ow_w[(k + 1) * EE + lane], s1);
        s2 = fmaf(h_s[w][k + 2], Ow_w[(k + 2) * EE + lane], s2);
        s3 = fmaf(h_s[w][k + 3], Ow_w[(k + 3) * EE + lane], s3);
      }
      const float a = owb + ((s0 + s1) + (s2 + s3));
      out[(size_t)fnode * EE + lane] = fmaxf(a, 0.f);
    }
    // no trailing barrier: next window's LDS writes are >=1 barrier away;
    // xb0 staging was drained at B4.
  }
}

// ---------------- R1 fallback (all-f32, no workspace) ----------------
template <int K>
__device__ __forceinline__ void mm2(const float* row0, const float* row1,
                                    const float* __restrict__ W, int e,
                                    float& acc0, float& acc1) {
  const float4* r0 = (const float4*)row0;
  const float4* r1 = (const float4*)row1;
#pragma unroll 4
  for (int k4 = 0; k4 < K / 4; ++k4) {
    float4 va = r0[k4];
    float4 vb = r1[k4];
    const float* w = W + (k4 * 4) * EE + e;
    float w0 = w[0], w1 = w[EE], w2 = w[2 * EE], w3 = w[3 * EE];
    acc0 = fmaf(va.x, w0, acc0);  acc1 = fmaf(vb.x, w0, acc1);
    acc0 = fmaf(va.y, w1, acc0);  acc1 = fmaf(vb.y, w1, acc1);
    acc0 = fmaf(va.z, w2, acc0);  acc1 = fmaf(vb.z, w2, acc1);
    acc0 = fmaf(va.w, w3, acc0);  acc1 = fmaf(vb.w, w3, acc1);
  }
}

__global__ __launch_bounds__(256, 4)
void postenc_kernel(
    const float* __restrict__ u2e, const float* __restrict__ r2e,
    const float* __restrict__ content_emb,
    const float* __restrict__ We_w, const float* __restrict__ We_b,
    const float* __restrict__ W1_w, const float* __restrict__ W1_b,
    const float* __restrict__ W2_w, const float* __restrict__ W2_b,
    const float* __restrict__ A1_w, const float* __restrict__ A1_b,
    const float* __restrict__ A2_w, const float* __restrict__ A2_b,
    const float* __restrict__ A3_w, const float* __restrict__ A3_b,
    const float* __restrict__ Ow_w, const float* __restrict__ Ow_b,
    const int* __restrict__ pu_history, const int* __restrict__ pr_history,
    const int* __restrict__ lengths, const int* __restrict__ pr_content,
    float* __restrict__ out) {
  const int n = blockIdx.x;
  const int tid = (int)threadIdx.x;
  const int e = tid & 63;
  const int g = tid >> 6;

  __shared__ float post_s[EE];
  __shared__ float abase_s[EE];
  __shared__ float in_s[8][128];
  __shared__ float x_s[8][EE];
  __shared__ float a_s[8][EE];
  __shared__ float o_s[56][EE];
  __shared__ float logit_s[EE];
  __shared__ float att_s[EE];
  __shared__ float red_s[4][EE];

  const int len = lengths[n];
  float p = 0.f;

  if (g == 0) {
    const float* ce = content_emb + (size_t)pr_content[n] * 128;
    float acc = We_b[e];
#pragma unroll 4
    for (int k = 0; k < 128; ++k) acc = fmaf(ce[k], We_w[k * EE + e], acc);
    p = fmaxf(acc, 0.f);
    post_s[e] = p;
    float ab = A1_b[e];
#pragma unroll
    for (int k = 0; k < 64; ++k) {
      float pk = __shfl(p, k);
      ab = fmaf(pk, A1_w[(64 + k) * EE + e], ab);
    }
    abase_s[e] = ab;
    logit_s[e] = -INFINITY;
  }
  __syncthreads();

  for (int lb = 0; lb < 56; lb += 8) {
    const int l0 = lb + g;
    const int l1 = l0 + 4;
    const bool v0 = l0 < LL;
    const bool v1 = l1 < LL;

    int pu0 = 0, pr0 = 0, pu1 = 0, pr1 = 0;
    if (v0) { pu0 = pu_history[n * LL + l0]; pr0 = pr_history[n * LL + l0]; }
    if (v1) { pu1 = pu_history[n * LL + l1]; pr1 = pr_history[n * LL + l1]; }
    in_s[g][e]          = v0 ? u2e[(size_t)pu0 * EE + e] : 0.f;
    in_s[g][64 + e]     = v0 ? r2e[pr0 * EE + e]         : 0.f;
    in_s[g + 4][e]      = v1 ? u2e[(size_t)pu1 * EE + e] : 0.f;
    in_s[g + 4][64 + e] = v1 ? r2e[pr1 * EE + e]         : 0.f;
    __syncthreads();

    float acc0 = W1_b[e], acc1 = acc0;
    mm2<128>(in_s[g], in_s[g + 4], W1_w, e, acc0, acc1);
    x_s[g][e]     = fmaxf(acc0, 0.f);
    x_s[g + 4][e] = fmaxf(acc1, 0.f);
    __syncthreads();

    acc0 = W2_b[e]; acc1 = acc0;
    mm2<64>(x_s[g], x_s[g + 4], W2_w, e, acc0, acc1);
    float o0 = fmaxf(acc0, 0.f);
    float o1 = fmaxf(acc1, 0.f);
    if (v0) o_s[l0][e] = o0;
    if (v1) o_s[l1][e] = o1;
    x_s[g][e]     = o0;
    x_s[g + 4][e] = o1;
    __syncthreads();

    acc0 = abase_s[e]; acc1 = acc0;
    mm2<64>(x_s[g], x_s[g + 4], A1_w, e, acc0, acc1);
    a_s[g][e]     = fmaxf(acc0, 0.f);
    a_s[g + 4][e] = fmaxf(acc1, 0.f);
    __syncthreads();

    acc0 = A2_b[e]; acc1 = acc0;
    mm2<64>(a_s[g], a_s[g + 4], A2_w, e, acc0, acc1);
    float w3 = A3_w[e];
    float p0 = fmaxf(acc0, 0.f) * w3;
    float p1 = fmaxf(acc1, 0.f) * w3;
#pragma unroll
    for (int off = 32; off > 0; off >>= 1) {
      p0 += __shfl_xor(p0, off);
      p1 += __shfl_xor(p1, off);
    }
    if (e == 0) {
      float b3 = A3_b[0];
      if (l0 < len) logit_s[l0] = p0 + b3;
      if (l1 < len) logit_s[l1] = p1 + b3;
    }
    __syncthreads();
  }

  if (g == 0) {
    float lg = logit_s[e];
    float m = lg;
#pragma unroll
    for (int off = 32; off > 0; off >>= 1) m = fmaxf(m, __shfl_xor(m, off));
    float pe = __expf(lg - m);
    float sm = pe;
#pragma unroll
    for (int off = 32; off > 0; off >>= 1) sm += __shfl_xor(sm, off);
    att_s[e] = pe / sm;
  }
  __syncthreads();

  {
    const int l_lo = 13 * g;
    const int l_hi = (13 * g + 13 < LL) ? 13 * g + 13 : LL;
    float h = 0.f;
    for (int l = l_lo; l < l_hi; ++l) h = fmaf(att_s[l], o_s[l][e], h);
    red_s[g][e] = h;
  }
  __syncthreads();

  if (g == 0) {
    float h = red_s[0][e] + red_s[1][e] + red_s[2][e] + red_s[3][e];
    float acc = Ow_b[e];
#pragma unroll
    for (int k = 0; k < 64; ++k) {
      float hk = __shfl(h, k);
      acc = fmaf(hk, Ow_w[k * EE + e], acc);
    }
#pragma unroll
    for (int k = 0; k < 64; ++k) {
      float pk = __shfl(p, k);
      acc = fmaf(pk, Ow_w[(64 + k) * EE + e], acc);
    }
    out[(size_t)n * EE + e] = fmaxf(acc, 0.f);
  }
}

// ---------------- launcher ----------------
extern "C" void kernel_launch(void* const* d_in, const int* in_sizes, int n_in,
                              void* d_out, int out_size, void* d_ws, size_t ws_size,
                              hipStream_t stream) {
  const float* u2e         = (const float*)d_in[0];
  const float* r2e         = (const float*)d_in[1];
  const float* content_emb = (const float*)d_in[2];
  const float* We_w = (const float*)d_in[3];
  const float* We_b = (const float*)d_in[4];
  const float* W1_w = (const float*)d_in[5];
  const float* W1_b = (const float*)d_in[6];
  const float* W2_w = (const float*)d_in[7];
  const float* W2_b = (const float*)d_in[8];
  const float* A1_w = (const float*)d_in[9];
  const float* A1_b = (const float*)d_in[10];
  const float* A2_w = (const float*)d_in[11];
  const float* A2_b = (const float*)d_in[12];
  const float* A3_w = (const float*)d_in[13];
  const float* A3_b = (const float*)d_in[14];
  const float* Ow_w = (const float*)d_in[15];
  const float* Ow_b = (const float*)d_in[16];
  // d_in[17] = nodes (unused)
  const int* pu_history = (const int*)d_in[18];
  const int* pr_history = (const int*)d_in[19];
  const int* lengths    = (const int*)d_in[20];
  const int* pr_content = (const int*)d_in[21];
  float* out = (float*)d_out;

  // workspace layout (bytes)
  const size_t FR_OFF  = 0;                               // frags 40960B
  const size_t PO_OFF  = 65536;
  const size_t AB_OFF  = PO_OFF + (size_t)NN * EE * 4;    // +4MB
  const size_t UBF_OFF = AB_OFF + (size_t)NN * EE * 4;    // +4MB
  const size_t CNT_OFF = UBF_OFF + (size_t)(NUE + 384) * 2;
  const size_t BK_OFF  = CNT_OFF + 256;
  const size_t WD_OFF  = BK_OFF + (size_t)4 * NN * 4;
  const size_t NEED    = WD_OFF + (size_t)NN * 4 * 4;     // ~20.8 MB

  if (ws_size < NEED) {
    postenc_kernel<<<NN, 256, 0, stream>>>(
        u2e, r2e, content_emb, We_w, We_b, W1_w, W1_b, W2_w, W2_b,
        A1_w, A1_b, A2_w, A2_b, A3_w, A3_b, Ow_w, Ow_b,
        pu_history, pr_history, lengths, pr_content, out);
    return;
  }

  char* wsp = (char*)d_ws;
  unsigned short* frag_ws = (unsigned short*)(wsp + FR_OFF);
  float* post_ws  = (float*)(wsp + PO_OFF);
  float* abase_ws = (float*)(wsp + AB_OFF);
  unsigned short* ur_bf = (unsigned short*)(wsp + UBF_OFF);
  int* Wout_ws = (int*)(wsp + CNT_OFF);
  int* bk_ws   = (int*)(wsp + BK_OFF);
  int* wd_ws   = (int*)(wsp + WD_OFF);

  pre_kernel<<<1540, 1024, 0, stream>>>(
      u2e, r2e, content_emb, pr_content, We_w, We_b, W1_w, W2_w,
      A1_w, A1_b, A2_w, lengths, ur_bf, bk_ws, wd_ws, Wout_ws,
      frag_ws, post_ws, abase_ws);
  fused_kernel<<<1024, 256, 0, stream>>>(
      ur_bf, W1_b, W2_b, A2_b, A3_w, A3_b, Ow_w, Ow_b,
      pu_history, pr_history, (const short8*)frag_ws,
      post_ws, abase_ws, wd_ws, Wout_ws, out);
}